// Round 1
// baseline (142.001 us; speedup 1.0000x reference)
//
#include <hip/hip_runtime.h>
#include <hip/hip_fp16.h>
#include <cstdint>
#include <cstddef>

typedef _Float16 f16;
typedef __attribute__((ext_vector_type(8))) _Float16 f16x8;
typedef __attribute__((ext_vector_type(4))) _Float16 f16x4;
typedef __attribute__((ext_vector_type(4))) float f32x4;

#define S_LEN 4096
#define D_DIM 1024

// ---------------------------------------------------------------------------
// async global->LDS 16B (CK-style addrspace casts via uintptr_t)
// ---------------------------------------------------------------------------
__device__ __forceinline__ void gld_lds16(const void* g, void* l) {
    auto gp = reinterpret_cast<const unsigned int __attribute__((address_space(1)))*>(
        reinterpret_cast<uintptr_t>(g));
    auto lp = reinterpret_cast<unsigned int __attribute__((address_space(3)))*>(
        reinterpret_cast<uintptr_t>(l));
    __builtin_amdgcn_global_load_lds(gp, lp, 16, 0, 0);
}

// ---------------------------------------------------------------------------
// Convert Q,K f32 -> f16 (vectorized float4 -> half4)
// ---------------------------------------------------------------------------
__global__ __launch_bounds__(256)
void convert_qk(const float* __restrict__ Q, const float* __restrict__ K,
                f16* __restrict__ Qh, f16* __restrict__ Kh)
{
    int idx = blockIdx.x * 256 + threadIdx.x;   // float4 index, total 2M
    const int NQ4 = S_LEN * D_DIM / 4;          // 1M float4 per tensor
    const float* src;
    f16* dst;
    int i = idx;
    if (i < NQ4) { src = Q; dst = Qh; }
    else         { src = K; dst = Kh; i -= NQ4; }
    float4 v = ((const float4*)src)[i];
    f16x4 h = {(_Float16)v.x, (_Float16)v.y, (_Float16)v.z, (_Float16)v.w};
    *(f16x4*)&dst[(size_t)i * 4] = h;
}

// ---------------------------------------------------------------------------
// Transpose V [4096][1024] f32 -> Vt [1024][4096] f16 (32x32 LDS tiles)
// ---------------------------------------------------------------------------
__global__ __launch_bounds__(256)
void transpose_v(const float* __restrict__ V, f16* __restrict__ Vt)
{
    __shared__ float tile[32][33];
    int tx = threadIdx.x & 31;
    int ty = threadIdx.x >> 5;      // 0..7
    int bx = blockIdx.x;            // along D (32 tiles)
    int by = blockIdx.y;            // along S (128 tiles)
#pragma unroll
    for (int j = 0; j < 4; ++j)
        tile[ty + j * 8][tx] = V[(size_t)(by * 32 + ty + j * 8) * D_DIM + bx * 32 + tx];
    __syncthreads();
#pragma unroll
    for (int j = 0; j < 4; ++j)
        Vt[(size_t)(bx * 32 + ty + j * 8) * S_LEN + by * 32 + tx] =
            (_Float16)tile[tx][ty + j * 8];
}

// ---------------------------------------------------------------------------
// NT GEMM: C[M][N] f32 = A[M][K] f16 row-major  x  B[N][K] f16 row-major
// 128x128 tile, BK=32, 4 waves (2x2), mfma_f32_16x16x32_f16,
// global_load_lds staging with pre-swizzled source (linear LDS dest).
// LDS 16B-slot (row,pos) holds k-block kb = pos ^ ((row>>1)&3).
// ---------------------------------------------------------------------------
__global__ __launch_bounds__(256, 2)
void gemm_nt_f16(const f16* __restrict__ A, const f16* __restrict__ B,
                 float* __restrict__ C, int N, int K,
                 int lda, int ldb, int ldc)
{
    __shared__ f16 sA[2][128 * 32];
    __shared__ f16 sB[2][128 * 32];

    const int tid = threadIdx.x;
    const int w = tid >> 6;          // wave 0..3
    const int l = tid & 63;
    const int lr = l & 15;           // row/col within frag
    const int lk = l >> 4;           // k-block 0..3
    const int wm = w >> 1, wn = w & 1;

    // bijective XCD swizzle (gridDim.x % 8 == 0 guaranteed by launch)
    const int nbx = N >> 7;
    const int cpx = gridDim.x >> 3;
    const int bid = blockIdx.x;
    const int swz = (bid & 7) * cpx + (bid >> 3);
    const int tm = (swz / nbx) * 128;
    const int tn = (swz % nbx) * 128;

    const int NT = K >> 5;           // K / 32

    auto stage = [&](int buf, int t) {
        const int kt = t << 5;
#pragma unroll
        for (int i = 0; i < 2; ++i) {
            const int sbase = (i * 4 + w) << 6;     // wave-uniform slot base
            const int s = sbase + l;
            const int row = s >> 2;
            const int pos = s & 3;
            const int kb = pos ^ ((row >> 1) & 3);  // pre-swizzled source
            gld_lds16(A + (size_t)(tm + row) * lda + kt + kb * 8, &sA[buf][sbase * 8]);
            gld_lds16(B + (size_t)(tn + row) * ldb + kt + kb * 8, &sB[buf][sbase * 8]);
        }
    };

    f32x4 acc[4][4] = {};

    stage(0, 0);
    __syncthreads();

    for (int t = 0; t < NT; ++t) {
        const int buf = t & 1;
        if (t + 1 < NT) stage(buf ^ 1, t + 1);

        f16x8 af[4], bf[4];
#pragma unroll
        for (int mi = 0; mi < 4; ++mi) {
            const int ra = wm * 64 + mi * 16 + lr;
            const int pa = lk ^ ((ra >> 1) & 3);
            af[mi] = *(const f16x8*)&sA[buf][(ra * 4 + pa) * 8];
            const int rb = wn * 64 + mi * 16 + lr;
            const int pb = lk ^ ((rb >> 1) & 3);
            bf[mi] = *(const f16x8*)&sB[buf][(rb * 4 + pb) * 8];
        }
#pragma unroll
        for (int mi = 0; mi < 4; ++mi)
#pragma unroll
            for (int ni = 0; ni < 4; ++ni)
                acc[mi][ni] = __builtin_amdgcn_mfma_f32_16x16x32_f16(
                    af[mi], bf[ni], acc[mi][ni], 0, 0, 0);

        __syncthreads();   // drains vmcnt (next tile staged) + lgkm, then barrier
    }

    // epilogue: C/D layout col=lane&15, row=(lane>>4)*4+reg  [m89-verified]
#pragma unroll
    for (int mi = 0; mi < 4; ++mi) {
        const int r0 = tm + wm * 64 + mi * 16 + (l >> 4) * 4;
#pragma unroll
        for (int ni = 0; ni < 4; ++ni) {
            const int c0 = tn + wn * 64 + ni * 16 + lr;
#pragma unroll
            for (int j = 0; j < 4; ++j)
                C[(size_t)(r0 + j) * ldc + c0] = acc[mi][ni][j];
        }
    }
}

// ---------------------------------------------------------------------------
// Row softmax: scores f32 [4096][4096] -> P f16, one block (256 thr) per row.
// Row held in registers (16 f32/thread).
// ---------------------------------------------------------------------------
__global__ __launch_bounds__(256)
void softmax_rows(const float* __restrict__ Sc, f16* __restrict__ P)
{
    const int r = blockIdx.x;
    const int t = threadIdx.x;
    const float* row = Sc + (size_t)r * S_LEN;

    float4 v[4];
#pragma unroll
    for (int c = 0; c < 4; ++c) v[c] = ((const float4*)row)[c * 256 + t];

    float m = -1e30f;
#pragma unroll
    for (int c = 0; c < 4; ++c)
        m = fmaxf(m, fmaxf(fmaxf(v[c].x, v[c].y), fmaxf(v[c].z, v[c].w)));
#pragma unroll
    for (int off = 32; off > 0; off >>= 1) m = fmaxf(m, __shfl_xor(m, off, 64));

    __shared__ float redm[4];
    __shared__ float reds[4];
    if ((t & 63) == 0) redm[t >> 6] = m;
    __syncthreads();
    m = fmaxf(fmaxf(redm[0], redm[1]), fmaxf(redm[2], redm[3]));

    float sum = 0.f;
#pragma unroll
    for (int c = 0; c < 4; ++c) {
        v[c].x = __expf(v[c].x - m);
        v[c].y = __expf(v[c].y - m);
        v[c].z = __expf(v[c].z - m);
        v[c].w = __expf(v[c].w - m);
        sum += (v[c].x + v[c].y) + (v[c].z + v[c].w);
    }
#pragma unroll
    for (int off = 32; off > 0; off >>= 1) sum += __shfl_xor(sum, off, 64);
    if ((t & 63) == 0) reds[t >> 6] = sum;
    __syncthreads();
    sum = (reds[0] + reds[1]) + (reds[2] + reds[3]);

    const float inv = 1.0f / sum;
#pragma unroll
    for (int c = 0; c < 4; ++c) {
        f16x4 h = {(_Float16)(v[c].x * inv), (_Float16)(v[c].y * inv),
                   (_Float16)(v[c].z * inv), (_Float16)(v[c].w * inv)};
        *(f16x4*)&P[(size_t)r * S_LEN + (size_t)(c * 256 + t) * 4] = h;
    }
}

// ---------------------------------------------------------------------------
// Fallback (only if ws too small): naive 2-pass attention, 1 block per row.
// ---------------------------------------------------------------------------
__global__ __launch_bounds__(256)
void attn_naive(const float* __restrict__ Q, const float* __restrict__ K,
                const float* __restrict__ V, float* __restrict__ O)
{
    const int r = blockIdx.x;
    const int t = threadIdx.x;
    __shared__ float red[4];
    float q[4];
#pragma unroll
    for (int i = 0; i < 4; ++i) q[i] = Q[(size_t)r * D_DIM + t + i * 256];

    float m = -1e30f;
    for (int j = 0; j < S_LEN; ++j) {
        float p = 0.f;
#pragma unroll
        for (int i = 0; i < 4; ++i) p += q[i] * K[(size_t)j * D_DIM + t + i * 256];
#pragma unroll
        for (int off = 32; off > 0; off >>= 1) p += __shfl_xor(p, off, 64);
        if ((t & 63) == 0) red[t >> 6] = p;
        __syncthreads();
        float s = (red[0] + red[1]) + (red[2] + red[3]);
        __syncthreads();
        m = fmaxf(m, s);
    }
    float acc[4] = {0.f, 0.f, 0.f, 0.f};
    float lsum = 0.f;
    for (int j = 0; j < S_LEN; ++j) {
        float p = 0.f;
#pragma unroll
        for (int i = 0; i < 4; ++i) p += q[i] * K[(size_t)j * D_DIM + t + i * 256];
#pragma unroll
        for (int off = 32; off > 0; off >>= 1) p += __shfl_xor(p, off, 64);
        if ((t & 63) == 0) red[t >> 6] = p;
        __syncthreads();
        float s = (red[0] + red[1]) + (red[2] + red[3]);
        __syncthreads();
        float e = __expf(s - m);
        lsum += e;
#pragma unroll
        for (int i = 0; i < 4; ++i) acc[i] += e * V[(size_t)j * D_DIM + t + i * 256];
    }
    const float inv = 1.f / lsum;
#pragma unroll
    for (int i = 0; i < 4; ++i) O[(size_t)r * D_DIM + t + i * 256] = acc[i] * inv;
}

// ---------------------------------------------------------------------------
extern "C" void kernel_launch(void* const* d_in, const int* in_sizes, int n_in,
                              void* d_out, int out_size, void* d_ws, size_t ws_size,
                              hipStream_t stream)
{
    const float* Q = (const float*)d_in[0];
    const float* K = (const float*)d_in[1];
    const float* V = (const float*)d_in[2];
    float* O = (float*)d_out;

    const size_t MB = 1024ull * 1024ull;
    const size_t QH_OFF = 0;
    const size_t KH_OFF = 8 * MB;
    const size_t VT_OFF = 16 * MB;
    const size_t SC_OFF = 24 * MB;   // 64 MB scores f32
    const size_t P_OFF  = 88 * MB;   // 32 MB P f16
    const size_t NEED   = 120 * MB;

    if (ws_size < NEED) {
        attn_naive<<<S_LEN, 256, 0, stream>>>(Q, K, V, O);
        return;
    }

    char* ws = (char*)d_ws;
    f16*   Qh = (f16*)(ws + QH_OFF);
    f16*   Kh = (f16*)(ws + KH_OFF);
    f16*   Vt = (f16*)(ws + VT_OFF);
    float* Sc = (float*)(ws + SC_OFF);
    f16*   P  = (f16*)(ws + P_OFF);

    convert_qk<<<2 * S_LEN * D_DIM / 4 / 256, 256, 0, stream>>>(Q, K, Qh, Kh);
    transpose_v<<<dim3(D_DIM / 32, S_LEN / 32), 256, 0, stream>>>(V, Vt);

    // scores = Qh * Kh^T : M=N=4096, K=1024
    gemm_nt_f16<<<(S_LEN / 128) * (S_LEN / 128), 256, 0, stream>>>(
        Qh, Kh, Sc, S_LEN, D_DIM, D_DIM, D_DIM, S_LEN);

    softmax_rows<<<S_LEN, 256, 0, stream>>>(Sc, P);

    // out = P * Vt^T : M=4096, N=1024, K=4096
    gemm_nt_f16<<<(S_LEN / 128) * (D_DIM / 128), 256, 0, stream>>>(
        P, Vt, O, D_DIM, S_LEN, S_LEN, S_LEN, D_DIM);
}

// Round 2
// 122.551 us; speedup vs baseline: 1.1587x; 1.1587x over previous
//
#include <hip/hip_runtime.h>
#include <hip/hip_fp16.h>
#include <cstdint>
#include <cstddef>

typedef _Float16 f16;
typedef __attribute__((ext_vector_type(8))) _Float16 f16x8;
typedef __attribute__((ext_vector_type(4))) _Float16 f16x4;
typedef __attribute__((ext_vector_type(4))) float f32x4;

#define S_LEN 4096
#define D_DIM 1024

// ---------------------------------------------------------------------------
// async global->LDS 16B
// ---------------------------------------------------------------------------
__device__ __forceinline__ void gld_lds16(const void* g, void* l) {
    auto gp = reinterpret_cast<const unsigned int __attribute__((address_space(1)))*>(
        reinterpret_cast<uintptr_t>(g));
    auto lp = reinterpret_cast<unsigned int __attribute__((address_space(3)))*>(
        reinterpret_cast<uintptr_t>(l));
    __builtin_amdgcn_global_load_lds(gp, lp, 16, 0, 0);
}

// ---------------------------------------------------------------------------
// Convert Q,K f32 -> f16
// ---------------------------------------------------------------------------
__global__ __launch_bounds__(256)
void convert_qk(const float* __restrict__ Q, const float* __restrict__ K,
                f16* __restrict__ Qh, f16* __restrict__ Kh)
{
    int idx = blockIdx.x * 256 + threadIdx.x;
    const int NQ4 = S_LEN * D_DIM / 4;
    const float* src;
    f16* dst;
    int i = idx;
    if (i < NQ4) { src = Q; dst = Qh; }
    else         { src = K; dst = Kh; i -= NQ4; }
    float4 v = ((const float4*)src)[i];
    f16x4 h = {(_Float16)v.x, (_Float16)v.y, (_Float16)v.z, (_Float16)v.w};
    *(f16x4*)&dst[(size_t)i * 4] = h;
}

// ---------------------------------------------------------------------------
// Transpose V [4096][1024] f32 -> Vt [1024][4096] f16
// ---------------------------------------------------------------------------
__global__ __launch_bounds__(256)
void transpose_v(const float* __restrict__ V, f16* __restrict__ Vt)
{
    __shared__ float tile[32][33];
    int tx = threadIdx.x & 31;
    int ty = threadIdx.x >> 5;
    int bx = blockIdx.x;
    int by = blockIdx.y;
#pragma unroll
    for (int j = 0; j < 4; ++j)
        tile[ty + j * 8][tx] = V[(size_t)(by * 32 + ty + j * 8) * D_DIM + bx * 32 + tx];
    __syncthreads();
#pragma unroll
    for (int j = 0; j < 4; ++j)
        Vt[(size_t)(bx * 32 + ty + j * 8) * S_LEN + by * 32 + tx] =
            (_Float16)tile[tx][ty + j * 8];
}

// ---------------------------------------------------------------------------
// 256x256-tile NT GEMM, BK=32, 8 waves (2x4), 4-slot LDS ring, 2 phases/K-tile,
// counted vmcnt(4), raw s_barrier, setprio around MFMA clusters.
// C[M][N] f32 = A[M][K] f16 row-major x B[N][K] f16 row-major (per split).
// ---------------------------------------------------------------------------
__global__ __launch_bounds__(512, 2)
void gemm256(const f16* __restrict__ A, const f16* __restrict__ B,
             float* __restrict__ C, int lda, int ldb, int ldc,
             int Ksub, int tilesN, int nsplit, size_t csplit)
{
    __shared__ f16 sA[4][256 * 32];
    __shared__ f16 sB[4][256 * 32];

    const int tid = threadIdx.x;
    const int w = tid >> 6;          // wave 0..7
    const int l = tid & 63;
    const int lr = l & 15;
    const int lk = l >> 4;           // k-chunk 0..3
    const int wm = w >> 2;           // 0..1  (M half: 128 rows)
    const int wn = w & 3;            // 0..3  (N quarter: 64 cols)

    // bijective XCD swizzle (grid = 256, %8==0)
    const int cpx = gridDim.x >> 3;
    const int bid = blockIdx.x;
    const int swz = (bid & 7) * cpx + (bid >> 3);
    int split = 0, tidx = swz;
    if (nsplit > 1) { split = swz & (nsplit - 1); tidx = swz / nsplit; }
    const int tm = (tidx / tilesN) * 256;
    const int tn = (tidx % tilesN) * 256;
    const int koff = split * Ksub;
    float* Cp = C + (size_t)split * csplit;
    const int NT = Ksub >> 5;

    auto stageA = [&](int rs, int t) {
        const int kt = koff + (t << 5);
#pragma unroll
        for (int r = 0; r < 2; ++r) {
            const int sbase = r * 512 + (w << 6);    // wave-uniform slot base
            const int s = sbase + l;
            const int row = s >> 2;
            const int pos = s & 3;
            const int kb = pos ^ ((row >> 1) & 3);
            gld_lds16(A + (size_t)(tm + row) * lda + kt + kb * 8, &sA[rs][sbase * 8]);
        }
    };
    auto stageB = [&](int rs, int t) {
        const int kt = koff + (t << 5);
#pragma unroll
        for (int r = 0; r < 2; ++r) {
            const int sbase = r * 512 + (w << 6);
            const int s = sbase + l;
            const int row = s >> 2;
            const int pos = s & 3;
            const int kb = pos ^ ((row >> 1) & 3);
            gld_lds16(B + (size_t)(tn + row) * ldb + kt + kb * 8, &sB[rs][sbase * 8]);
        }
    };

    f32x4 acc[8][4] = {};

    // prologue: stage tiles 0,1 (8 loads/thread); wait tile 0 landed (4 in flight)
    stageA(0, 0); stageB(0, 0);
    stageA(1, 1); stageB(1, 1);
    asm volatile("s_waitcnt vmcnt(4)" ::: "memory");
    __builtin_amdgcn_s_barrier();

    for (int t = 0; t < NT; ++t) {
        const int rs = t & 3;
        const int ps = (t + 2) & 3;
        const bool pre = (t + 2) < NT;

        // ---------------- phase 0: mi 0..3 ----------------
        f16x8 af[4], bf[4];
#pragma unroll
        for (int mi = 0; mi < 4; ++mi) {
            const int ra = wm * 128 + mi * 16 + lr;
            const int sl = lk ^ ((ra >> 1) & 3);
            af[mi] = *(const f16x8*)&sA[rs][ra * 32 + sl * 8];
        }
#pragma unroll
        for (int ni = 0; ni < 4; ++ni) {
            const int rb = wn * 64 + ni * 16 + lr;
            const int sl = lk ^ ((rb >> 1) & 3);
            bf[ni] = *(const f16x8*)&sB[rs][rb * 32 + sl * 8];
        }
        if (pre) stageA(ps, t + 2);
        __builtin_amdgcn_s_barrier();
        asm volatile("s_waitcnt lgkmcnt(0)");
        __builtin_amdgcn_sched_barrier(0);
        __builtin_amdgcn_s_setprio(1);
#pragma unroll
        for (int mi = 0; mi < 4; ++mi)
#pragma unroll
            for (int ni = 0; ni < 4; ++ni)
                acc[mi][ni] = __builtin_amdgcn_mfma_f32_16x16x32_f16(
                    af[mi], bf[ni], acc[mi][ni], 0, 0, 0);
        __builtin_amdgcn_s_setprio(0);
        __builtin_amdgcn_s_barrier();

        // ---------------- phase 1: mi 4..7 ----------------
        f16x8 ag[4];
#pragma unroll
        for (int mi = 0; mi < 4; ++mi) {
            const int ra = wm * 128 + (mi + 4) * 16 + lr;
            const int sl = lk ^ ((ra >> 1) & 3);
            ag[mi] = *(const f16x8*)&sA[rs][ra * 32 + sl * 8];
        }
        if (pre) stageB(ps, t + 2);
        __builtin_amdgcn_s_barrier();
        asm volatile("s_waitcnt lgkmcnt(0)");
        __builtin_amdgcn_sched_barrier(0);
        __builtin_amdgcn_s_setprio(1);
#pragma unroll
        for (int mi = 0; mi < 4; ++mi)
#pragma unroll
            for (int ni = 0; ni < 4; ++ni)
                acc[mi + 4][ni] = __builtin_amdgcn_mfma_f32_16x16x32_f16(
                    ag[mi], bf[ni], acc[mi + 4][ni], 0, 0, 0);
        __builtin_amdgcn_s_setprio(0);
        // counted vmcnt: keep tile t+2's 4 loads in flight; tail drains once
        if (pre) {
            asm volatile("s_waitcnt vmcnt(4)" ::: "memory");
        } else if (t == NT - 2) {
            asm volatile("s_waitcnt vmcnt(0)" ::: "memory");
        }
        __builtin_amdgcn_s_barrier();
    }

    // epilogue: C/D layout col=lane&15, row=(lane>>4)*4+reg
#pragma unroll
    for (int mi = 0; mi < 8; ++mi) {
        const int r0 = tm + wm * 128 + mi * 16 + (l >> 4) * 4;
#pragma unroll
        for (int ni = 0; ni < 4; ++ni) {
            const int c0 = tn + wn * 64 + ni * 16 + lr;
#pragma unroll
            for (int j = 0; j < 4; ++j)
                Cp[(size_t)(r0 + j) * ldc + c0] = acc[mi][ni][j];
        }
    }
}

// ---------------------------------------------------------------------------
// Row softmax: scores f32 [4096][4096] -> P f16
// ---------------------------------------------------------------------------
__global__ __launch_bounds__(256)
void softmax_rows(const float* __restrict__ Sc, f16* __restrict__ P)
{
    const int r = blockIdx.x;
    const int t = threadIdx.x;
    const float* row = Sc + (size_t)r * S_LEN;

    float4 v[4];
#pragma unroll
    for (int c = 0; c < 4; ++c) v[c] = ((const float4*)row)[c * 256 + t];

    float m = -1e30f;
#pragma unroll
    for (int c = 0; c < 4; ++c)
        m = fmaxf(m, fmaxf(fmaxf(v[c].x, v[c].y), fmaxf(v[c].z, v[c].w)));
#pragma unroll
    for (int off = 32; off > 0; off >>= 1) m = fmaxf(m, __shfl_xor(m, off, 64));

    __shared__ float redm[4];
    __shared__ float reds[4];
    if ((t & 63) == 0) redm[t >> 6] = m;
    __syncthreads();
    m = fmaxf(fmaxf(redm[0], redm[1]), fmaxf(redm[2], redm[3]));

    float sum = 0.f;
#pragma unroll
    for (int c = 0; c < 4; ++c) {
        v[c].x = __expf(v[c].x - m);
        v[c].y = __expf(v[c].y - m);
        v[c].z = __expf(v[c].z - m);
        v[c].w = __expf(v[c].w - m);
        sum += (v[c].x + v[c].y) + (v[c].z + v[c].w);
    }
#pragma unroll
    for (int off = 32; off > 0; off >>= 1) sum += __shfl_xor(sum, off, 64);
    if ((t & 63) == 0) reds[t >> 6] = sum;
    __syncthreads();
    sum = (reds[0] + reds[1]) + (reds[2] + reds[3]);

    const float inv = 1.0f / sum;
#pragma unroll
    for (int c = 0; c < 4; ++c) {
        f16x4 h = {(_Float16)(v[c].x * inv), (_Float16)(v[c].y * inv),
                   (_Float16)(v[c].z * inv), (_Float16)(v[c].w * inv)};
        *(f16x4*)&P[(size_t)r * S_LEN + (size_t)(c * 256 + t) * 4] = h;
    }
}

// ---------------------------------------------------------------------------
// Combine 4 split-K partials -> O
// ---------------------------------------------------------------------------
__global__ __launch_bounds__(256)
void combine4(const float* __restrict__ Pt, float* __restrict__ O)
{
    const size_t i = (size_t)blockIdx.x * 256 + threadIdx.x;
    const size_t n4 = (size_t)S_LEN * D_DIM / 4;
    const float4* p = (const float4*)Pt;
    float4 a = p[i], b = p[i + n4], c = p[i + 2 * n4], d = p[i + 3 * n4];
    float4 r;
    r.x = (a.x + b.x) + (c.x + d.x);
    r.y = (a.y + b.y) + (c.y + d.y);
    r.z = (a.z + b.z) + (c.z + d.z);
    r.w = (a.w + b.w) + (c.w + d.w);
    ((float4*)O)[i] = r;
}

// ---------------------------------------------------------------------------
// Fallback: naive 2-pass attention
// ---------------------------------------------------------------------------
__global__ __launch_bounds__(256)
void attn_naive(const float* __restrict__ Q, const float* __restrict__ K,
                const float* __restrict__ V, float* __restrict__ O)
{
    const int r = blockIdx.x;
    const int t = threadIdx.x;
    __shared__ float red[4];
    float q[4];
#pragma unroll
    for (int i = 0; i < 4; ++i) q[i] = Q[(size_t)r * D_DIM + t + i * 256];

    float m = -1e30f;
    for (int j = 0; j < S_LEN; ++j) {
        float p = 0.f;
#pragma unroll
        for (int i = 0; i < 4; ++i) p += q[i] * K[(size_t)j * D_DIM + t + i * 256];
#pragma unroll
        for (int off = 32; off > 0; off >>= 1) p += __shfl_xor(p, off, 64);
        if ((t & 63) == 0) red[t >> 6] = p;
        __syncthreads();
        float s = (red[0] + red[1]) + (red[2] + red[3]);
        __syncthreads();
        m = fmaxf(m, s);
    }
    float acc[4] = {0.f, 0.f, 0.f, 0.f};
    float lsum = 0.f;
    for (int j = 0; j < S_LEN; ++j) {
        float p = 0.f;
#pragma unroll
        for (int i = 0; i < 4; ++i) p += q[i] * K[(size_t)j * D_DIM + t + i * 256];
#pragma unroll
        for (int off = 32; off > 0; off >>= 1) p += __shfl_xor(p, off, 64);
        if ((t & 63) == 0) red[t >> 6] = p;
        __syncthreads();
        float s = (red[0] + red[1]) + (red[2] + red[3]);
        __syncthreads();
        float e = __expf(s - m);
        lsum += e;
#pragma unroll
        for (int i = 0; i < 4; ++i) acc[i] += e * V[(size_t)j * D_DIM + t + i * 256];
    }
    const float inv = 1.f / lsum;
#pragma unroll
    for (int i = 0; i < 4; ++i) O[(size_t)r * D_DIM + t + i * 256] = acc[i] * inv;
}

// ---------------------------------------------------------------------------
extern "C" void kernel_launch(void* const* d_in, const int* in_sizes, int n_in,
                              void* d_out, int out_size, void* d_ws, size_t ws_size,
                              hipStream_t stream)
{
    const float* Q = (const float*)d_in[0];
    const float* K = (const float*)d_in[1];
    const float* V = (const float*)d_in[2];
    float* O = (float*)d_out;

    const size_t MB = 1024ull * 1024ull;
    const size_t QH_OFF = 0;
    const size_t KH_OFF = 8 * MB;
    const size_t VT_OFF = 16 * MB;
    const size_t SC_OFF = 24 * MB;   // 64 MB: scores f32, then split-K partials
    const size_t P_OFF  = 88 * MB;   // 32 MB P f16
    const size_t NEED   = 120 * MB;

    if (ws_size < NEED) {
        attn_naive<<<S_LEN, 256, 0, stream>>>(Q, K, V, O);
        return;
    }

    char* ws = (char*)d_ws;
    f16*   Qh = (f16*)(ws + QH_OFF);
    f16*   Kh = (f16*)(ws + KH_OFF);
    f16*   Vt = (f16*)(ws + VT_OFF);
    float* Sc = (float*)(ws + SC_OFF);
    f16*   P  = (f16*)(ws + P_OFF);

    convert_qk<<<2 * S_LEN * D_DIM / 4 / 256, 256, 0, stream>>>(Q, K, Qh, Kh);
    transpose_v<<<dim3(D_DIM / 32, S_LEN / 32), 256, 0, stream>>>(V, Vt);

    // scores = Qh * Kh^T : M=N=4096, K=1024 -> 16x16 tiles = 256 blocks
    gemm256<<<256, 512, 0, stream>>>(Qh, Kh, Sc, D_DIM, D_DIM, S_LEN,
                                     D_DIM, 16, 1, 0);

    softmax_rows<<<S_LEN, 256, 0, stream>>>(Sc, P);

    // out = P * Vt^T : M=4096, N=1024, K=4096, split-K=4 -> 16x4x4 = 256 blocks
    // partials overwrite the (now dead) scores region: 4 x 16 MiB = 64 MiB
    gemm256<<<256, 512, 0, stream>>>(P, Vt, Sc, S_LEN, S_LEN, D_DIM,
                                     D_DIM, 4, 4, (size_t)S_LEN * D_DIM);

    combine4<<<S_LEN * D_DIM / 4 / 256, 256, 0, stream>>>(Sc, O);
}

// Round 3
// 117.430 us; speedup vs baseline: 1.2092x; 1.0436x over previous
//
#include <hip/hip_runtime.h>
#include <hip/hip_fp16.h>
#include <cstdint>
#include <cstddef>

typedef _Float16 f16;
typedef __attribute__((ext_vector_type(8))) _Float16 f16x8;
typedef __attribute__((ext_vector_type(4))) _Float16 f16x4;
typedef __attribute__((ext_vector_type(4))) float f32x4;

#define S_LEN 4096
#define D_DIM 1024

template<int N> struct IC { static constexpr int v = N; };

// ---------------------------------------------------------------------------
// async global->LDS 16B
// ---------------------------------------------------------------------------
__device__ __forceinline__ void gld_lds16(const void* g, void* l) {
    auto gp = reinterpret_cast<const unsigned int __attribute__((address_space(1)))*>(
        reinterpret_cast<uintptr_t>(g));
    auto lp = reinterpret_cast<unsigned int __attribute__((address_space(3)))*>(
        reinterpret_cast<uintptr_t>(l));
    __builtin_amdgcn_global_load_lds(gp, lp, 16, 0, 0);
}

// ---------------------------------------------------------------------------
// Fused prep: convert Q,K f32->f16 (blocks 0..8191) and transpose V (8192..)
// ---------------------------------------------------------------------------
__global__ __launch_bounds__(256)
void prep(const float* __restrict__ Q, const float* __restrict__ K,
          const float* __restrict__ V,
          f16* __restrict__ Qh, f16* __restrict__ Kh, f16* __restrict__ Vt)
{
    const int b = blockIdx.x;
    if (b < 8192) {
        int idx = b * 256 + threadIdx.x;
        const int NQ4 = S_LEN * D_DIM / 4;
        const float* src;
        f16* dst;
        int i = idx;
        if (i < NQ4) { src = Q; dst = Qh; }
        else         { src = K; dst = Kh; i -= NQ4; }
        float4 v = ((const float4*)src)[i];
        f16x4 h = {(_Float16)v.x, (_Float16)v.y, (_Float16)v.z, (_Float16)v.w};
        *(f16x4*)&dst[(size_t)i * 4] = h;
    } else {
        __shared__ float tile[32][33];
        const int bb = b - 8192;
        const int bx = bb & 31;          // along D (32 tiles)
        const int by = bb >> 5;          // along S (128 tiles)
        const int tx = threadIdx.x & 31;
        const int ty = threadIdx.x >> 5;
#pragma unroll
        for (int j = 0; j < 4; ++j)
            tile[ty + j * 8][tx] = V[(size_t)(by * 32 + ty + j * 8) * D_DIM + bx * 32 + tx];
        __syncthreads();
#pragma unroll
        for (int j = 0; j < 4; ++j)
            Vt[(size_t)(bx * 32 + ty + j * 8) * S_LEN + by * 32 + tx] =
                (_Float16)tile[tx][ty + j * 8];
    }
}

// ---------------------------------------------------------------------------
// 256x256-tile NT GEMM, BK=32, 8 waves (2x4), 4-slot LDS ring, prefetch
// depth 3 (vmcnt(6) steady, 6->4->0 tail), cross-phase register read
// pipelining with counted lgkmcnt(4/8), setprio around MFMA clusters.
// C[M][N] f32 = A[M][K] f16 row-major x B[N][K] f16 row-major (per split).
// ---------------------------------------------------------------------------
__global__ __launch_bounds__(512, 2)
void gemm256(const f16* __restrict__ A, const f16* __restrict__ B,
             float* __restrict__ C, int lda, int ldb, int ldc,
             int Ksub, int tilesN, int nsplit, size_t csplit)
{
    __shared__ f16 sA[4][256 * 32];
    __shared__ f16 sB[4][256 * 32];

    const int tid = threadIdx.x;
    const int w = tid >> 6;          // wave 0..7
    const int l = tid & 63;
    const int lr = l & 15;
    const int lk = l >> 4;           // k-chunk 0..3
    const int wm = w >> 2;           // 0..1  (M half: 128 rows)
    const int wn = w & 3;            // 0..3  (N quarter: 64 cols)

    // bijective XCD swizzle (grid = 256, %8==0)
    const int cpx = gridDim.x >> 3;
    const int bid = blockIdx.x;
    const int swz = (bid & 7) * cpx + (bid >> 3);
    int split = 0, tidx = swz;
    if (nsplit > 1) { split = swz & (nsplit - 1); tidx = swz / nsplit; }
    const int tm = (tidx / tilesN) * 256;
    const int tn = (tidx % tilesN) * 256;
    const int koff = split * Ksub;
    float* Cp = C + (size_t)split * csplit;
    const int NT = Ksub >> 5;        // K-tiles of 32 (>= 8, even)

    // precomputed per-thread fragment offsets (f16 elements within a slot)
    int offA[8], offB[4];
#pragma unroll
    for (int mi = 0; mi < 8; ++mi) {
        const int ra = wm * 128 + mi * 16 + lr;
        offA[mi] = ra * 32 + (lk ^ ((ra >> 1) & 3)) * 8;
    }
#pragma unroll
    for (int ni = 0; ni < 4; ++ni) {
        const int rb = wn * 64 + ni * 16 + lr;
        offB[ni] = rb * 32 + (lk ^ ((rb >> 1) & 3)) * 8;
    }

    auto stageA = [&](int rs, int t) {
        const int kt = koff + (t << 5);
#pragma unroll
        for (int r = 0; r < 2; ++r) {
            const int sbase = r * 512 + (w << 6);    // wave-uniform slot base
            const int s = sbase + l;
            const int row = s >> 2;
            const int pos = s & 3;
            const int kb = pos ^ ((row >> 1) & 3);
            gld_lds16(A + (size_t)(tm + row) * lda + kt + kb * 8, &sA[rs][sbase * 8]);
        }
    };
    auto stageB = [&](int rs, int t) {
        const int kt = koff + (t << 5);
#pragma unroll
        for (int r = 0; r < 2; ++r) {
            const int sbase = r * 512 + (w << 6);
            const int s = sbase + l;
            const int row = s >> 2;
            const int pos = s & 3;
            const int kb = pos ^ ((row >> 1) & 3);
            gld_lds16(B + (size_t)(tn + row) * ldb + kt + kb * 8, &sB[rs][sbase * 8]);
        }
    };

    f32x4 acc[8][4] = {};
    f16x8 afA[4], bfA[4], afB[4], bfB[4];

    // prologue: stage tiles 0,1,2 -> wait tile 0 (8 loads outstanding)
    stageA(0, 0); stageB(0, 0);
    stageA(1, 1); stageB(1, 1);
    stageA(2, 2); stageB(2, 2);
    asm volatile("s_waitcnt vmcnt(8)" ::: "memory");
    __builtin_amdgcn_s_barrier();
    __builtin_amdgcn_sched_barrier(0);
#pragma unroll
    for (int i = 0; i < 4; ++i) afA[i] = *(const f16x8*)(&sA[0][0] + offA[i]);
#pragma unroll
    for (int i = 0; i < 4; ++i) bfA[i] = *(const f16x8*)(&sB[0][0] + offB[i]);

    // one K-tile step. af/bf = current tile frags (loaded last phase),
    // afn/bfn = next tile frags (loaded this ph1).
    auto tstep = [&](auto VMN, auto STG, auto LD1,
                     f16x8* af, f16x8* bf, f16x8* afn, f16x8* bfn, int t) {
        constexpr int vmn = decltype(VMN)::v;
        constexpr bool stg = decltype(STG)::v;
        constexpr bool ld1 = decltype(LD1)::v;
        const f16* sa = &sA[t & 3][0];

        // -------- phase 0: prefetch ag (for ph1), stage A(t+3) --------
        __builtin_amdgcn_sched_barrier(0);
        f16x8 ag[4];
#pragma unroll
        for (int i = 0; i < 4; ++i) ag[i] = *(const f16x8*)(sa + offA[i + 4]);
        if constexpr (stg) stageA((t + 3) & 3, t + 3);
        __builtin_amdgcn_s_barrier();
        asm volatile("s_waitcnt lgkmcnt(4)" ::: "memory");   // drain af,bf; keep ag
        __builtin_amdgcn_sched_barrier(0);
        __builtin_amdgcn_s_setprio(1);
#pragma unroll
        for (int mi = 0; mi < 4; ++mi)
#pragma unroll
            for (int ni = 0; ni < 4; ++ni)
                acc[mi][ni] = __builtin_amdgcn_mfma_f32_16x16x32_f16(
                    af[mi], bf[ni], acc[mi][ni], 0, 0, 0);
        __builtin_amdgcn_s_setprio(0);
        // ensure slot t+1 landed (counted; 6 steady, 4/0 at tail)
        if constexpr (vmn == 6)      asm volatile("s_waitcnt vmcnt(6)" ::: "memory");
        else if constexpr (vmn == 4) asm volatile("s_waitcnt vmcnt(4)" ::: "memory");
        else                         asm volatile("s_waitcnt vmcnt(0)" ::: "memory");
        __builtin_amdgcn_s_barrier();

        // -------- phase 1: prefetch next tile frags, stage B(t+3) --------
        __builtin_amdgcn_sched_barrier(0);
        if constexpr (ld1) {
            const f16* na = &sA[(t + 1) & 3][0];
            const f16* nb = &sB[(t + 1) & 3][0];
#pragma unroll
            for (int i = 0; i < 4; ++i) afn[i] = *(const f16x8*)(na + offA[i]);
#pragma unroll
            for (int i = 0; i < 4; ++i) bfn[i] = *(const f16x8*)(nb + offB[i]);
        }
        if constexpr (stg) stageB((t + 3) & 3, t + 3);
        __builtin_amdgcn_s_barrier();
        if constexpr (ld1) asm volatile("s_waitcnt lgkmcnt(8)" ::: "memory");  // drain ag; keep afn,bfn
        else               asm volatile("s_waitcnt lgkmcnt(0)" ::: "memory");
        __builtin_amdgcn_sched_barrier(0);
        __builtin_amdgcn_s_setprio(1);
#pragma unroll
        for (int mi = 0; mi < 4; ++mi)
#pragma unroll
            for (int ni = 0; ni < 4; ++ni)
                acc[mi + 4][ni] = __builtin_amdgcn_mfma_f32_16x16x32_f16(
                    ag[mi], bf[ni], acc[mi + 4][ni], 0, 0, 0);
        __builtin_amdgcn_s_setprio(0);
        __builtin_amdgcn_s_barrier();
    };

    // main loop: tiles 0..NT-5 (uniform: stage valid, vmcnt(6))
    for (int u = 0; u < NT / 2 - 2; ++u) {
        tstep(IC<6>{}, IC<true>{}, IC<true>{}, afA, bfA, afB, bfB, 2 * u);
        tstep(IC<6>{}, IC<true>{}, IC<true>{}, afB, bfB, afA, bfA, 2 * u + 1);
    }
    // tail: tiles NT-4 .. NT-1 with vmcnt ladder 6 -> 4 -> 0 -> 0
    tstep(IC<6>{}, IC<true>{},  IC<true>{},  afA, bfA, afB, bfB, NT - 4);
    tstep(IC<4>{}, IC<false>{}, IC<true>{},  afB, bfB, afA, bfA, NT - 3);
    tstep(IC<0>{}, IC<false>{}, IC<true>{},  afA, bfA, afB, bfB, NT - 2);
    tstep(IC<0>{}, IC<false>{}, IC<false>{}, afB, bfB, afA, bfA, NT - 1);

    // epilogue: C/D layout col=lane&15, row=(lane>>4)*4+reg
#pragma unroll
    for (int mi = 0; mi < 8; ++mi) {
        const int r0 = tm + wm * 128 + mi * 16 + (l >> 4) * 4;
#pragma unroll
        for (int ni = 0; ni < 4; ++ni) {
            const int c0 = tn + wn * 64 + ni * 16 + lr;
#pragma unroll
            for (int j = 0; j < 4; ++j)
                Cp[(size_t)(r0 + j) * ldc + c0] = acc[mi][ni][j];
        }
    }
}

// ---------------------------------------------------------------------------
// Row softmax: scores f32 [4096][4096] -> P f16
// ---------------------------------------------------------------------------
__global__ __launch_bounds__(256)
void softmax_rows(const float* __restrict__ Sc, f16* __restrict__ P)
{
    const int r = blockIdx.x;
    const int t = threadIdx.x;
    const float* row = Sc + (size_t)r * S_LEN;

    float4 v[4];
#pragma unroll
    for (int c = 0; c < 4; ++c) v[c] = ((const float4*)row)[c * 256 + t];

    float m = -1e30f;
#pragma unroll
    for (int c = 0; c < 4; ++c)
        m = fmaxf(m, fmaxf(fmaxf(v[c].x, v[c].y), fmaxf(v[c].z, v[c].w)));
#pragma unroll
    for (int off = 32; off > 0; off >>= 1) m = fmaxf(m, __shfl_xor(m, off, 64));

    __shared__ float redm[4];
    __shared__ float reds[4];
    if ((t & 63) == 0) redm[t >> 6] = m;
    __syncthreads();
    m = fmaxf(fmaxf(redm[0], redm[1]), fmaxf(redm[2], redm[3]));

    float sum = 0.f;
#pragma unroll
    for (int c = 0; c < 4; ++c) {
        v[c].x = __expf(v[c].x - m);
        v[c].y = __expf(v[c].y - m);
        v[c].z = __expf(v[c].z - m);
        v[c].w = __expf(v[c].w - m);
        sum += (v[c].x + v[c].y) + (v[c].z + v[c].w);
    }
#pragma unroll
    for (int off = 32; off > 0; off >>= 1) sum += __shfl_xor(sum, off, 64);
    if ((t & 63) == 0) reds[t >> 6] = sum;
    __syncthreads();
    sum = (reds[0] + reds[1]) + (reds[2] + reds[3]);

    const float inv = 1.0f / sum;
#pragma unroll
    for (int c = 0; c < 4; ++c) {
        f16x4 h = {(_Float16)(v[c].x * inv), (_Float16)(v[c].y * inv),
                   (_Float16)(v[c].z * inv), (_Float16)(v[c].w * inv)};
        *(f16x4*)&P[(size_t)r * S_LEN + (size_t)(c * 256 + t) * 4] = h;
    }
}

// ---------------------------------------------------------------------------
// Combine 4 split-K partials -> O
// ---------------------------------------------------------------------------
__global__ __launch_bounds__(256)
void combine4(const float* __restrict__ Pt, float* __restrict__ O)
{
    const size_t i = (size_t)blockIdx.x * 256 + threadIdx.x;
    const size_t n4 = (size_t)S_LEN * D_DIM / 4;
    const float4* p = (const float4*)Pt;
    float4 a = p[i], b = p[i + n4], c = p[i + 2 * n4], d = p[i + 3 * n4];
    float4 r;
    r.x = (a.x + b.x) + (c.x + d.x);
    r.y = (a.y + b.y) + (c.y + d.y);
    r.z = (a.z + b.z) + (c.z + d.z);
    r.w = (a.w + b.w) + (c.w + d.w);
    ((float4*)O)[i] = r;
}

// ---------------------------------------------------------------------------
// Fallback: naive 2-pass attention
// ---------------------------------------------------------------------------
__global__ __launch_bounds__(256)
void attn_naive(const float* __restrict__ Q, const float* __restrict__ K,
                const float* __restrict__ V, float* __restrict__ O)
{
    const int r = blockIdx.x;
    const int t = threadIdx.x;
    __shared__ float red[4];
    float q[4];
#pragma unroll
    for (int i = 0; i < 4; ++i) q[i] = Q[(size_t)r * D_DIM + t + i * 256];

    float m = -1e30f;
    for (int j = 0; j < S_LEN; ++j) {
        float p = 0.f;
#pragma unroll
        for (int i = 0; i < 4; ++i) p += q[i] * K[(size_t)j * D_DIM + t + i * 256];
#pragma unroll
        for (int off = 32; off > 0; off >>= 1) p += __shfl_xor(p, off, 64);
        if ((t & 63) == 0) red[t >> 6] = p;
        __syncthreads();
        float s = (red[0] + red[1]) + (red[2] + red[3]);
        __syncthreads();
        m = fmaxf(m, s);
    }
    float acc[4] = {0.f, 0.f, 0.f, 0.f};
    float lsum = 0.f;
    for (int j = 0; j < S_LEN; ++j) {
        float p = 0.f;
#pragma unroll
        for (int i = 0; i < 4; ++i) p += q[i] * K[(size_t)j * D_DIM + t + i * 256];
#pragma unroll
        for (int off = 32; off > 0; off >>= 1) p += __shfl_xor(p, off, 64);
        if ((t & 63) == 0) red[t >> 6] = p;
        __syncthreads();
        float s = (red[0] + red[1]) + (red[2] + red[3]);
        __syncthreads();
        float e = __expf(s - m);
        lsum += e;
#pragma unroll
        for (int i = 0; i < 4; ++i) acc[i] += e * V[(size_t)j * D_DIM + t + i * 256];
    }
    const float inv = 1.f / lsum;
#pragma unroll
    for (int i = 0; i < 4; ++i) O[(size_t)r * D_DIM + t + i * 256] = acc[i] * inv;
}

// ---------------------------------------------------------------------------
extern "C" void kernel_launch(void* const* d_in, const int* in_sizes, int n_in,
                              void* d_out, int out_size, void* d_ws, size_t ws_size,
                              hipStream_t stream)
{
    const float* Q = (const float*)d_in[0];
    const float* K = (const float*)d_in[1];
    const float* V = (const float*)d_in[2];
    float* O = (float*)d_out;

    const size_t MB = 1024ull * 1024ull;
    const size_t QH_OFF = 0;
    const size_t KH_OFF = 8 * MB;
    const size_t VT_OFF = 16 * MB;
    const size_t SC_OFF = 24 * MB;   // 64 MB: scores f32, then split-K partials
    const size_t P_OFF  = 88 * MB;   // 32 MB P f16
    const size_t NEED   = 120 * MB;

    if (ws_size < NEED) {
        attn_naive<<<S_LEN, 256, 0, stream>>>(Q, K, V, O);
        return;
    }

    char* ws = (char*)d_ws;
    f16*   Qh = (f16*)(ws + QH_OFF);
    f16*   Kh = (f16*)(ws + KH_OFF);
    f16*   Vt = (f16*)(ws + VT_OFF);
    float* Sc = (float*)(ws + SC_OFF);
    f16*   P  = (f16*)(ws + P_OFF);

    // convert Q,K (blocks 0..8191) + transpose V (blocks 8192..12287)
    prep<<<8192 + 4096, 256, 0, stream>>>(Q, K, V, Qh, Kh, Vt);

    // scores = Qh * Kh^T : M=N=4096, K=1024 -> 16x16 tiles = 256 blocks
    gemm256<<<256, 512, 0, stream>>>(Qh, Kh, Sc, D_DIM, D_DIM, S_LEN,
                                     D_DIM, 16, 1, 0);

    softmax_rows<<<S_LEN, 256, 0, stream>>>(Sc, P);

    // out = P * Vt^T : M=4096, N=1024, K=4096, split-K=4 -> 16x4x4 = 256 blocks
    gemm256<<<256, 512, 0, stream>>>(P, Vt, Sc, S_LEN, S_LEN, D_DIM,
                                     D_DIM, 4, 4, (size_t)S_LEN * D_DIM);

    combine4<<<S_LEN * D_DIM / 4 / 256, 256, 0, stream>>>(Sc, O);
}

// Round 4
// 112.554 us; speedup vs baseline: 1.2616x; 1.0433x over previous
//
#include <hip/hip_runtime.h>
#include <hip/hip_fp16.h>
#include <cstdint>
#include <cstddef>

typedef _Float16 f16;
typedef __attribute__((ext_vector_type(8))) _Float16 f16x8;
typedef __attribute__((ext_vector_type(4))) _Float16 f16x4;
typedef __attribute__((ext_vector_type(4))) float f32x4;

#define S_LEN 4096
#define D_DIM 1024
#define SOFT_C 160.0f

template<int N> struct IC { static constexpr int v = N; };

__device__ __forceinline__ void gld_lds16(const void* g, void* l) {
    auto gp = reinterpret_cast<const unsigned int __attribute__((address_space(1)))*>(
        reinterpret_cast<uintptr_t>(g));
    auto lp = reinterpret_cast<unsigned int __attribute__((address_space(3)))*>(
        reinterpret_cast<uintptr_t>(l));
    __builtin_amdgcn_global_load_lds(gp, lp, 16, 0, 0);
}

template<int N> __device__ __forceinline__ void wait_vm() {
    if constexpr (N == 10)     asm volatile("s_waitcnt vmcnt(10)" ::: "memory");
    else if constexpr (N == 8) asm volatile("s_waitcnt vmcnt(8)" ::: "memory");
    else if constexpr (N == 6) asm volatile("s_waitcnt vmcnt(6)" ::: "memory");
    else if constexpr (N == 4) asm volatile("s_waitcnt vmcnt(4)" ::: "memory");
    else if constexpr (N == 2) asm volatile("s_waitcnt vmcnt(2)" ::: "memory");
    else if constexpr (N == 0) asm volatile("s_waitcnt vmcnt(0)" ::: "memory");
    // N < 0: no wait
}

// ---------------------------------------------------------------------------
// Fused prep: convert Q,K f32->f16 (blocks 0..8191) and transpose V (8192..)
// ---------------------------------------------------------------------------
__global__ __launch_bounds__(256)
void prep(const float* __restrict__ Q, const float* __restrict__ K,
          const float* __restrict__ V,
          f16* __restrict__ Qh, f16* __restrict__ Kh, f16* __restrict__ Vt)
{
    const int b = blockIdx.x;
    if (b < 8192) {
        int idx = b * 256 + threadIdx.x;
        const int NQ4 = S_LEN * D_DIM / 4;
        const float* src;
        f16* dst;
        int i = idx;
        if (i < NQ4) { src = Q; dst = Qh; }
        else         { src = K; dst = Kh; i -= NQ4; }
        float4 v = ((const float4*)src)[i];
        f16x4 h = {(_Float16)v.x, (_Float16)v.y, (_Float16)v.z, (_Float16)v.w};
        *(f16x4*)&dst[(size_t)i * 4] = h;
    } else {
        __shared__ float tile[32][33];
        const int bb = b - 8192;
        const int bx = bb & 31;
        const int by = bb >> 5;
        const int tx = threadIdx.x & 31;
        const int ty = threadIdx.x >> 5;
#pragma unroll
        for (int j = 0; j < 4; ++j)
            tile[ty + j * 8][tx] = V[(size_t)(by * 32 + ty + j * 8) * D_DIM + bx * 32 + tx];
        __syncthreads();
#pragma unroll
        for (int j = 0; j < 4; ++j)
            Vt[(size_t)(bx * 32 + ty + j * 8) * S_LEN + by * 32 + tx] =
                (_Float16)tile[tx][ty + j * 8];
    }
}

// ---------------------------------------------------------------------------
// GEMM1: E = exp(Qh*Kh^T - C), 256x256 tile, BK=32, proven R3 loop.
// Epilogue: exp + store E f32 + per-(tileN,row) partial row sums (determin.)
// ---------------------------------------------------------------------------
__global__ __launch_bounds__(512, 2)
void gemm_exp(const f16* __restrict__ A, const f16* __restrict__ B,
              float* __restrict__ C, float* __restrict__ psum,
              int lda, int ldb, int ldc, int K, int tilesN)
{
    __shared__ f16 sA[4][256 * 32];
    __shared__ f16 sB[4][256 * 32];

    const int tid = threadIdx.x;
    const int w = tid >> 6;
    const int l = tid & 63;
    const int lr = l & 15;
    const int lk = l >> 4;
    const int wm = w >> 2;
    const int wn = w & 3;

    const int cpx = gridDim.x >> 3;
    const int bid = blockIdx.x;
    const int swz = (bid & 7) * cpx + (bid >> 3);
    const int tm = (swz / tilesN) * 256;
    const int tn = (swz % tilesN) * 256;
    const int NT = K >> 5;

    int offA[8], offB[4];
#pragma unroll
    for (int mi = 0; mi < 8; ++mi) {
        const int ra = wm * 128 + mi * 16 + lr;
        offA[mi] = ra * 32 + (lk ^ ((ra >> 1) & 3)) * 8;
    }
#pragma unroll
    for (int ni = 0; ni < 4; ++ni) {
        const int rb = wn * 64 + ni * 16 + lr;
        offB[ni] = rb * 32 + (lk ^ ((rb >> 1) & 3)) * 8;
    }

    auto stageA = [&](int rs, int t) {
        const int kt = t << 5;
#pragma unroll
        for (int r = 0; r < 2; ++r) {
            const int sbase = r * 512 + (w << 6);
            const int s = sbase + l;
            const int row = s >> 2;
            const int pos = s & 3;
            const int kb = pos ^ ((row >> 1) & 3);
            gld_lds16(A + (size_t)(tm + row) * lda + kt + kb * 8, &sA[rs][sbase * 8]);
        }
    };
    auto stageB = [&](int rs, int t) {
        const int kt = t << 5;
#pragma unroll
        for (int r = 0; r < 2; ++r) {
            const int sbase = r * 512 + (w << 6);
            const int s = sbase + l;
            const int row = s >> 2;
            const int pos = s & 3;
            const int kb = pos ^ ((row >> 1) & 3);
            gld_lds16(B + (size_t)(tn + row) * ldb + kt + kb * 8, &sB[rs][sbase * 8]);
        }
    };

    f32x4 acc[8][4] = {};
    f16x8 afA[4], bfA[4], afB[4], bfB[4];

    stageA(0, 0); stageB(0, 0);
    stageA(1, 1); stageB(1, 1);
    stageA(2, 2); stageB(2, 2);
    asm volatile("s_waitcnt vmcnt(8)" ::: "memory");
    __builtin_amdgcn_s_barrier();
    __builtin_amdgcn_sched_barrier(0);
#pragma unroll
    for (int i = 0; i < 4; ++i) afA[i] = *(const f16x8*)(&sA[0][0] + offA[i]);
#pragma unroll
    for (int i = 0; i < 4; ++i) bfA[i] = *(const f16x8*)(&sB[0][0] + offB[i]);

    auto tstep = [&](auto VMN, auto STG, auto LD1,
                     f16x8* af, f16x8* bf, f16x8* afn, f16x8* bfn, int t) {
        constexpr int vmn = decltype(VMN)::v;
        constexpr bool stg = decltype(STG)::v;
        constexpr bool ld1 = decltype(LD1)::v;
        const f16* sa = &sA[t & 3][0];

        __builtin_amdgcn_sched_barrier(0);
        f16x8 ag[4];
#pragma unroll
        for (int i = 0; i < 4; ++i) ag[i] = *(const f16x8*)(sa + offA[i + 4]);
        if constexpr (stg) stageA((t + 3) & 3, t + 3);
        __builtin_amdgcn_s_barrier();
        asm volatile("s_waitcnt lgkmcnt(4)" ::: "memory");
        __builtin_amdgcn_sched_barrier(0);
        __builtin_amdgcn_s_setprio(1);
#pragma unroll
        for (int mi = 0; mi < 4; ++mi)
#pragma unroll
            for (int ni = 0; ni < 4; ++ni)
                acc[mi][ni] = __builtin_amdgcn_mfma_f32_16x16x32_f16(
                    af[mi], bf[ni], acc[mi][ni], 0, 0, 0);
        __builtin_amdgcn_s_setprio(0);
        wait_vm<vmn>();
        __builtin_amdgcn_s_barrier();

        __builtin_amdgcn_sched_barrier(0);
        if constexpr (ld1) {
            const f16* na = &sA[(t + 1) & 3][0];
            const f16* nb = &sB[(t + 1) & 3][0];
#pragma unroll
            for (int i = 0; i < 4; ++i) afn[i] = *(const f16x8*)(na + offA[i]);
#pragma unroll
            for (int i = 0; i < 4; ++i) bfn[i] = *(const f16x8*)(nb + offB[i]);
        }
        if constexpr (stg) stageB((t + 3) & 3, t + 3);
        __builtin_amdgcn_s_barrier();
        if constexpr (ld1) asm volatile("s_waitcnt lgkmcnt(8)" ::: "memory");
        else               asm volatile("s_waitcnt lgkmcnt(0)" ::: "memory");
        __builtin_amdgcn_sched_barrier(0);
        __builtin_amdgcn_s_setprio(1);
#pragma unroll
        for (int mi = 0; mi < 4; ++mi)
#pragma unroll
            for (int ni = 0; ni < 4; ++ni)
                acc[mi + 4][ni] = __builtin_amdgcn_mfma_f32_16x16x32_f16(
                    ag[mi], bf[ni], acc[mi + 4][ni], 0, 0, 0);
        __builtin_amdgcn_s_setprio(0);
        __builtin_amdgcn_s_barrier();
    };

    for (int u = 0; u < NT / 2 - 2; ++u) {
        tstep(IC<6>{}, IC<true>{}, IC<true>{}, afA, bfA, afB, bfB, 2 * u);
        tstep(IC<6>{}, IC<true>{}, IC<true>{}, afB, bfB, afA, bfA, 2 * u + 1);
    }
    tstep(IC<6>{}, IC<true>{},  IC<true>{},  afA, bfA, afB, bfB, NT - 4);
    tstep(IC<4>{}, IC<false>{}, IC<true>{},  afB, bfB, afA, bfA, NT - 3);
    tstep(IC<0>{}, IC<false>{}, IC<true>{},  afA, bfA, afB, bfB, NT - 2);
    tstep(IC<0>{}, IC<false>{}, IC<false>{}, afB, bfB, afA, bfA, NT - 1);

    // ---- epilogue: E = exp(s - C), store f32, reduce row partial sums ----
    float rs[8][4];
#pragma unroll
    for (int mi = 0; mi < 8; ++mi)
#pragma unroll
        for (int j = 0; j < 4; ++j) rs[mi][j] = 0.f;

#pragma unroll
    for (int mi = 0; mi < 8; ++mi) {
        const int r0 = tm + wm * 128 + mi * 16 + (l >> 4) * 4;
#pragma unroll
        for (int ni = 0; ni < 4; ++ni) {
            const int c0 = tn + wn * 64 + ni * 16 + lr;
#pragma unroll
            for (int j = 0; j < 4; ++j) {
                float e = __expf(acc[mi][ni][j] - SOFT_C);
                C[(size_t)(r0 + j) * ldc + c0] = e;
                rs[mi][j] += e;
            }
        }
    }
    // reduce over the 16 lanes (lr) holding different columns of same rows
#pragma unroll
    for (int mi = 0; mi < 8; ++mi)
#pragma unroll
        for (int j = 0; j < 4; ++j)
#pragma unroll
            for (int m = 1; m < 16; m <<= 1)
                rs[mi][j] += __shfl_xor(rs[mi][j], m, 64);

    float* lsum = (float*)&sA[0][0];   // [4 wn][256 rows]
    __syncthreads();
    if (lr == 0) {
#pragma unroll
        for (int mi = 0; mi < 8; ++mi)
#pragma unroll
            for (int j = 0; j < 4; ++j)
                lsum[wn * 256 + wm * 128 + mi * 16 + (l >> 4) * 4 + j] = rs[mi][j];
    }
    __syncthreads();
    if (tid < 256) {
        float s = (lsum[tid] + lsum[256 + tid]) + (lsum[512 + tid] + lsum[768 + tid]);
        psum[(size_t)(tn >> 8) * S_LEN + tm + tid] = s;
    }
}

// ---------------------------------------------------------------------------
// Row sums -> reciprocal
// ---------------------------------------------------------------------------
__global__ __launch_bounds__(256)
void sumrows(const float* __restrict__ ps, float* __restrict__ invR)
{
    const int r = blockIdx.x * 256 + threadIdx.x;
    float s = 0.f;
#pragma unroll
    for (int j = 0; j < 16; ++j) s += ps[(size_t)j * S_LEN + r];
    invR[r] = 1.0f / s;
}

// ---------------------------------------------------------------------------
// GEMM2: out_partial(f16) = (E*invR) x Vt^T, split-K=4, reg-staged A operand.
// M=4096 (16 tiles), N=1024 (4 tiles), Ksub=1024 (NT=32). 256 blocks.
// vmcnt schedule (hand-derived, see commit journal): steady ph0-end vmcnt(10)
// [drain B(t+1) gld], ph1 vmcnt(6) before A ds_write [drain A(t+2) reg loads];
// tail 6/2 -> 0. All ds_write drains (lgkmcnt(0)) precede barriers.
// ---------------------------------------------------------------------------
struct AReg { float4 v0, v1, v2, v3; };

__global__ __launch_bounds__(512, 2)
void gemm_rega(const float* __restrict__ E, const f16* __restrict__ B,
               const float* __restrict__ invR,
               f16* __restrict__ P01, f16* __restrict__ P23)
{
    __shared__ f16 sA[4][256 * 32];
    __shared__ f16 sB[4][256 * 32];

    const int tid = threadIdx.x;
    const int w = tid >> 6;
    const int l = tid & 63;
    const int lr = l & 15;
    const int lk = l >> 4;
    const int wm = w >> 2;
    const int wn = w & 3;

    const int cpx = gridDim.x >> 3;
    const int bid = blockIdx.x;
    const int swz = (bid & 7) * cpx + (bid >> 3);
    const int split = swz & 3;
    const int tidx = swz >> 2;
    const int tm = (tidx >> 2) * 256;      // tilesN = 4
    const int tn = (tidx & 3) * 256;
    const int koff = split * 1024;
    f16* Cp = (split < 2) ? (P01 + (size_t)split * (S_LEN * D_DIM))
                          : (P23 + (size_t)(split - 2) * (S_LEN * D_DIM));
    const int NT = 32;

    int offA[8], offB[4];
#pragma unroll
    for (int mi = 0; mi < 8; ++mi) {
        const int ra = wm * 128 + mi * 16 + lr;
        offA[mi] = ra * 32 + (lk ^ ((ra >> 1) & 3)) * 8;
    }
#pragma unroll
    for (int ni = 0; ni < 4; ++ni) {
        const int rb = wn * 64 + ni * 16 + lr;
        offB[ni] = rb * 32 + (lk ^ ((rb >> 1) & 3)) * 8;
    }

    // staging geometry: this thread's two 16B chunks (8 f16 each)
    const int s0 = (w << 6) + l;
    const int row0 = s0 >> 2;
    const int pos0 = s0 & 3;
    const int kb0 = pos0 ^ ((row0 >> 1) & 3);
    const int row1 = row0 + 128;            // same pos/kb

    const float inv0v = invR[tm + row0];
    const float inv1v = invR[tm + row1];
    asm volatile("s_waitcnt vmcnt(0)" ::: "memory");

    auto aload = [&](int t, AReg& r) {
        const int kt = koff + (t << 5);
        const float* p0 = E + (size_t)(tm + row0) * 4096 + kt + kb0 * 8;
        const float* p1 = E + (size_t)(tm + row1) * 4096 + kt + kb0 * 8;
        r.v0 = ((const float4*)p0)[0];
        r.v1 = ((const float4*)p0)[1];
        r.v2 = ((const float4*)p1)[0];
        r.v3 = ((const float4*)p1)[1];
    };
    auto awrite = [&](int rs, const AReg& r) {
        f16x8 h0, h1;
        h0[0] = (_Float16)(r.v0.x * inv0v); h0[1] = (_Float16)(r.v0.y * inv0v);
        h0[2] = (_Float16)(r.v0.z * inv0v); h0[3] = (_Float16)(r.v0.w * inv0v);
        h0[4] = (_Float16)(r.v1.x * inv0v); h0[5] = (_Float16)(r.v1.y * inv0v);
        h0[6] = (_Float16)(r.v1.z * inv0v); h0[7] = (_Float16)(r.v1.w * inv0v);
        h1[0] = (_Float16)(r.v2.x * inv1v); h1[1] = (_Float16)(r.v2.y * inv1v);
        h1[2] = (_Float16)(r.v2.z * inv1v); h1[3] = (_Float16)(r.v2.w * inv1v);
        h1[4] = (_Float16)(r.v3.x * inv1v); h1[5] = (_Float16)(r.v3.y * inv1v);
        h1[6] = (_Float16)(r.v3.z * inv1v); h1[7] = (_Float16)(r.v3.w * inv1v);
        *(f16x8*)&sA[rs][(size_t)s0 * 8] = h0;
        *(f16x8*)&sA[rs][(size_t)(512 + s0) * 8] = h1;
    };
    auto bstage = [&](int rs, int t) {
        const int kt = koff + (t << 5);
#pragma unroll
        for (int r = 0; r < 2; ++r) {
            const int sbase = r * 512 + (w << 6);
            const int s = sbase + l;
            const int row = s >> 2;
            const int pos = s & 3;
            const int kb = pos ^ ((row >> 1) & 3);
            gld_lds16(B + (size_t)(tn + row) * 4096 + kt + kb * 8, &sB[rs][sbase * 8]);
        }
    };

    f32x4 acc[8][4] = {};
    AReg rA, rB;

    // prologue: slots 0,1,2 (A via reg-stage; B via gld_lds)
    aload(0, rA); aload(1, rB);
    bstage(0, 0); bstage(1, 1);                       // out: [A0:4,A1:4,B0:2,B1:2]
    asm volatile("s_waitcnt vmcnt(8)" ::: "memory");  // drain A0
    awrite(0, rA);
    aload(2, rA); bstage(2, 2);                       // out: [A1,B0,B1,A2,B2]=14
    asm volatile("s_waitcnt vmcnt(10)" ::: "memory"); // drain A1
    awrite(1, rB);
    asm volatile("s_waitcnt vmcnt(8)" ::: "memory");  // drain B0
    asm volatile("s_waitcnt lgkmcnt(0)" ::: "memory");
    __builtin_amdgcn_s_barrier();

    auto rstep = [&](auto VM0, auto VM1, auto AISS, auto BISS, auto AWRT,
                     AReg& rIss, AReg& rCons, int t) {
        constexpr int vm0 = decltype(VM0)::v;
        constexpr int vm1 = decltype(VM1)::v;
        constexpr bool aiss = decltype(AISS)::v;
        constexpr bool biss = decltype(BISS)::v;
        constexpr bool awrt = decltype(AWRT)::v;
        const f16* sa = &sA[t & 3][0];
        const f16* sb = &sB[t & 3][0];

        // ---- phase 0 ----
        __builtin_amdgcn_sched_barrier(0);
        f16x8 af[4], bf[4];
#pragma unroll
        for (int i = 0; i < 4; ++i) af[i] = *(const f16x8*)(sa + offA[i]);
#pragma unroll
        for (int i = 0; i < 4; ++i) bf[i] = *(const f16x8*)(sb + offB[i]);
        if constexpr (aiss) aload(t + 3, rIss);
        __builtin_amdgcn_s_barrier();
        asm volatile("s_waitcnt lgkmcnt(0)" ::: "memory");
        __builtin_amdgcn_sched_barrier(0);
        __builtin_amdgcn_s_setprio(1);
#pragma unroll
        for (int mi = 0; mi < 4; ++mi)
#pragma unroll
            for (int ni = 0; ni < 4; ++ni)
                acc[mi][ni] = __builtin_amdgcn_mfma_f32_16x16x32_f16(
                    af[mi], bf[ni], acc[mi][ni], 0, 0, 0);
        __builtin_amdgcn_s_setprio(0);
        wait_vm<vm0>();                     // drain B(t+1) gld (needed next ph0)
        __builtin_amdgcn_s_barrier();

        // ---- phase 1 ----
        __builtin_amdgcn_sched_barrier(0);
        f16x8 ag[4];
#pragma unroll
        for (int i = 0; i < 4; ++i) ag[i] = *(const f16x8*)(sa + offA[i + 4]);
        if constexpr (awrt) {
            wait_vm<vm1>();                 // drain A(t+2) reg loads
            awrite((t + 2) & 3, rCons);
        }
        if constexpr (biss) bstage((t + 3) & 3, t + 3);
        asm volatile("s_waitcnt lgkmcnt(0)" ::: "memory");  // drain ag + ds_writes (pre-barrier!)
        __builtin_amdgcn_s_barrier();
        __builtin_amdgcn_sched_barrier(0);
        __builtin_amdgcn_s_setprio(1);
#pragma unroll
        for (int mi = 0; mi < 4; ++mi)
#pragma unroll
            for (int ni = 0; ni < 4; ++ni)
                acc[mi + 4][ni] = __builtin_amdgcn_mfma_f32_16x16x32_f16(
                    ag[mi], bf[ni], acc[mi + 4][ni], 0, 0, 0);
        __builtin_amdgcn_s_setprio(0);
        __builtin_amdgcn_s_barrier();
    };

    // steady: t=0..27 (even: issue->rB consume rA; odd: issue->rA consume rB)
    for (int u = 0; u < 14; ++u) {
        rstep(IC<10>{}, IC<6>{}, IC<1>{}, IC<1>{}, IC<1>{}, rB, rA, 2 * u);
        rstep(IC<10>{}, IC<6>{}, IC<1>{}, IC<1>{}, IC<1>{}, rA, rB, 2 * u + 1);
    }
    // t=28 steady (issues A31->rB, B31; writes A30 from rA)
    rstep(IC<10>{}, IC<6>{}, IC<1>{}, IC<1>{}, IC<1>{}, rB, rA, 28);
    // t=29: no issues; write A31 from rB
    rstep(IC<6>{},  IC<2>{}, IC<0>{}, IC<0>{}, IC<1>{}, rA, rB, 29);
    // t=30: drain last B; no write
    rstep(IC<0>{},  IC<-1>{}, IC<0>{}, IC<0>{}, IC<0>{}, rA, rB, 30);
    // t=31: plain
    rstep(IC<-1>{}, IC<-1>{}, IC<0>{}, IC<0>{}, IC<0>{}, rA, rB, 31);

    // epilogue: f16 partial store
#pragma unroll
    for (int mi = 0; mi < 8; ++mi) {
        const int r0 = tm + wm * 128 + mi * 16 + (l >> 4) * 4;
#pragma unroll
        for (int ni = 0; ni < 4; ++ni) {
            const int c0 = tn + wn * 64 + ni * 16 + lr;
#pragma unroll
            for (int j = 0; j < 4; ++j)
                Cp[(size_t)(r0 + j) * D_DIM + c0] = (_Float16)acc[mi][ni][j];
        }
    }
}

// ---------------------------------------------------------------------------
// Combine 4 f16 split-K partials -> O f32
// ---------------------------------------------------------------------------
__global__ __launch_bounds__(256)
void combine4(const f16* __restrict__ P01, const f16* __restrict__ P23,
              float* __restrict__ O)
{
    const size_t i = (size_t)blockIdx.x * 256 + threadIdx.x;
    const size_t n = (size_t)S_LEN * D_DIM;
    f16x4 a = ((const f16x4*)P01)[i];
    f16x4 b = ((const f16x4*)(P01 + n))[i];
    f16x4 c = ((const f16x4*)P23)[i];
    f16x4 d = ((const f16x4*)(P23 + n))[i];
    float4 r;
    r.x = ((float)a[0] + (float)b[0]) + ((float)c[0] + (float)d[0]);
    r.y = ((float)a[1] + (float)b[1]) + ((float)c[1] + (float)d[1]);
    r.z = ((float)a[2] + (float)b[2]) + ((float)c[2] + (float)d[2]);
    r.w = ((float)a[3] + (float)b[3]) + ((float)c[3] + (float)d[3]);
    ((float4*)O)[i] = r;
}

// ---------------------------------------------------------------------------
// Fallback: naive 2-pass attention
// ---------------------------------------------------------------------------
__global__ __launch_bounds__(256)
void attn_naive(const float* __restrict__ Q, const float* __restrict__ K,
                const float* __restrict__ V, float* __restrict__ O)
{
    const int r = blockIdx.x;
    const int t = threadIdx.x;
    __shared__ float red[4];
    float q[4];
#pragma unroll
    for (int i = 0; i < 4; ++i) q[i] = Q[(size_t)r * D_DIM + t + i * 256];

    float m = -1e30f;
    for (int j = 0; j < S_LEN; ++j) {
        float p = 0.f;
#pragma unroll
        for (int i = 0; i < 4; ++i) p += q[i] * K[(size_t)j * D_DIM + t + i * 256];
#pragma unroll
        for (int off = 32; off > 0; off >>= 1) p += __shfl_xor(p, off, 64);
        if ((t & 63) == 0) red[t >> 6] = p;
        __syncthreads();
        float s = (red[0] + red[1]) + (red[2] + red[3]);
        __syncthreads();
        m = fmaxf(m, s);
    }
    float acc[4] = {0.f, 0.f, 0.f, 0.f};
    float lsum = 0.f;
    for (int j = 0; j < S_LEN; ++j) {
        float p = 0.f;
#pragma unroll
        for (int i = 0; i < 4; ++i) p += q[i] * K[(size_t)j * D_DIM + t + i * 256];
#pragma unroll
        for (int off = 32; off > 0; off >>= 1) p += __shfl_xor(p, off, 64);
        if ((t & 63) == 0) red[t >> 6] = p;
        __syncthreads();
        float s = (red[0] + red[1]) + (red[2] + red[3]);
        __syncthreads();
        float e = __expf(s - m);
        lsum += e;
#pragma unroll
        for (int i = 0; i < 4; ++i) acc[i] += e * V[(size_t)j * D_DIM + t + i * 256];
    }
    const float inv = 1.f / lsum;
#pragma unroll
    for (int i = 0; i < 4; ++i) O[(size_t)r * D_DIM + t + i * 256] = acc[i] * inv;
}

// ---------------------------------------------------------------------------
extern "C" void kernel_launch(void* const* d_in, const int* in_sizes, int n_in,
                              void* d_out, int out_size, void* d_ws, size_t ws_size,
                              hipStream_t stream)
{
    const float* Q = (const float*)d_in[0];
    const float* K = (const float*)d_in[1];
    const float* V = (const float*)d_in[2];
    float* O = (float*)d_out;

    const size_t MB = 1024ull * 1024ull;
    // layout: QH 0-8 (later GEMM2 partial split0/1 at 0-16), KH 8-16, VT 16-24,
    // E 24-88, PSUM 88, INV 89, P23 90-106
    const size_t QH_OFF = 0;
    const size_t KH_OFF = 8 * MB;
    const size_t VT_OFF = 16 * MB;
    const size_t E_OFF  = 24 * MB;
    const size_t PS_OFF = 88 * MB;
    const size_t IV_OFF = 89 * MB;
    const size_t P23_OFF = 90 * MB;
    const size_t NEED   = 120 * MB;

    if (ws_size < NEED) {
        attn_naive<<<S_LEN, 256, 0, stream>>>(Q, K, V, O);
        return;
    }

    char* ws = (char*)d_ws;
    f16*   Qh  = (f16*)(ws + QH_OFF);
    f16*   Kh  = (f16*)(ws + KH_OFF);
    f16*   Vt  = (f16*)(ws + VT_OFF);
    float* E   = (float*)(ws + E_OFF);
    float* ps  = (float*)(ws + PS_OFF);
    float* inv = (float*)(ws + IV_OFF);
    f16*   P01 = (f16*)(ws + QH_OFF);    // overwrites dead Qh/Kh
    f16*   P23 = (f16*)(ws + P23_OFF);

    prep<<<8192 + 4096, 256, 0, stream>>>(Q, K, V, Qh, Kh, Vt);

    // E = exp(Qh*Kh^T - C) + partial row sums
    gemm_exp<<<256, 512, 0, stream>>>(Qh, Kh, E, ps, D_DIM, D_DIM, S_LEN,
                                      D_DIM, 16);

    sumrows<<<16, 256, 0, stream>>>(ps, inv);

    // partials = (E*invR) x Vt^T, split-K=4, f16
    gemm_rega<<<256, 512, 0, stream>>>(E, Vt, inv, P01, P23);

    combine4<<<S_LEN * D_DIM / 4 / 256, 256, 0, stream>>>(P01, P23, O);
}

// Round 5
// 99.080 us; speedup vs baseline: 1.4332x; 1.1360x over previous
//
#include <hip/hip_runtime.h>
#include <hip/hip_fp16.h>
#include <cstdint>
#include <cstddef>

typedef _Float16 f16;
typedef __attribute__((ext_vector_type(8))) _Float16 f16x8;
typedef __attribute__((ext_vector_type(4))) _Float16 f16x4;
typedef __attribute__((ext_vector_type(8))) short s16x8;   // 8 x bf16
typedef __attribute__((ext_vector_type(4))) float f32x4;

#define S_LEN 4096
#define D_DIM 1024
#define SOFT_C 160.0f

template<int N> struct IC { static constexpr int v = N; };

__device__ __forceinline__ void gld_lds16(const void* g, void* l) {
    auto gp = reinterpret_cast<const unsigned int __attribute__((address_space(1)))*>(
        reinterpret_cast<uintptr_t>(g));
    auto lp = reinterpret_cast<unsigned int __attribute__((address_space(3)))*>(
        reinterpret_cast<uintptr_t>(l));
    __builtin_amdgcn_global_load_lds(gp, lp, 16, 0, 0);
}

template<int N> __device__ __forceinline__ void wait_vm() {
    if constexpr (N == 8)      asm volatile("s_waitcnt vmcnt(8)" ::: "memory");
    else if constexpr (N == 6) asm volatile("s_waitcnt vmcnt(6)" ::: "memory");
    else if constexpr (N == 4) asm volatile("s_waitcnt vmcnt(4)" ::: "memory");
    else if constexpr (N == 0) asm volatile("s_waitcnt vmcnt(0)" ::: "memory");
}

// float -> bf16 (round-to-nearest-even; inputs are finite normals here)
__device__ __forceinline__ unsigned short f2bf(float x) {
    unsigned u = __builtin_bit_cast(unsigned, x);
    u += 0x7FFFu + ((u >> 16) & 1u);
    return (unsigned short)(u >> 16);
}

// ---------------------------------------------------------------------------
// Fused prep: convert Q,K f32->f16 (blocks 0..8191); transpose V -> bf16
// ---------------------------------------------------------------------------
__global__ __launch_bounds__(256)
void prep(const float* __restrict__ Q, const float* __restrict__ K,
          const float* __restrict__ V,
          f16* __restrict__ Qh, f16* __restrict__ Kh, unsigned short* __restrict__ Vt)
{
    const int b = blockIdx.x;
    if (b < 8192) {
        int idx = b * 256 + threadIdx.x;
        const int NQ4 = S_LEN * D_DIM / 4;
        const float* src;
        f16* dst;
        int i = idx;
        if (i < NQ4) { src = Q; dst = Qh; }
        else         { src = K; dst = Kh; i -= NQ4; }
        float4 v = ((const float4*)src)[i];
        f16x4 h = {(_Float16)v.x, (_Float16)v.y, (_Float16)v.z, (_Float16)v.w};
        *(f16x4*)&dst[(size_t)i * 4] = h;
    } else {
        __shared__ float tile[32][33];
        const int bb = b - 8192;
        const int bx = bb & 31;
        const int by = bb >> 5;
        const int tx = threadIdx.x & 31;
        const int ty = threadIdx.x >> 5;
#pragma unroll
        for (int j = 0; j < 4; ++j)
            tile[ty + j * 8][tx] = V[(size_t)(by * 32 + ty + j * 8) * D_DIM + bx * 32 + tx];
        __syncthreads();
#pragma unroll
        for (int j = 0; j < 4; ++j)
            Vt[(size_t)(bx * 32 + ty + j * 8) * S_LEN + by * 32 + tx] =
                f2bf(tile[tx][ty + j * 8]);
    }
}

// ---------------------------------------------------------------------------
// GEMM1: E = exp(Qh*Kh^T - C) -> bf16, + per-(tileN,row) partial row sums.
// 256x256 tile, BK=32, f16 MFMA, proven R3 pipeline.
// ---------------------------------------------------------------------------
__global__ __launch_bounds__(512, 2)
void gemm_exp(const f16* __restrict__ A, const f16* __restrict__ B,
              unsigned short* __restrict__ C, float* __restrict__ psum,
              int lda, int ldb, int ldc, int K, int tilesN)
{
    __shared__ f16 sA[4][256 * 32];
    __shared__ f16 sB[4][256 * 32];

    const int tid = threadIdx.x;
    const int w = tid >> 6;
    const int l = tid & 63;
    const int lr = l & 15;
    const int lk = l >> 4;
    const int wm = w >> 2;
    const int wn = w & 3;

    const int cpx = gridDim.x >> 3;
    const int bid = blockIdx.x;
    const int swz = (bid & 7) * cpx + (bid >> 3);
    const int tm = (swz / tilesN) * 256;
    const int tn = (swz % tilesN) * 256;
    const int NT = K >> 5;

    int offA[8], offB[4];
#pragma unroll
    for (int mi = 0; mi < 8; ++mi) {
        const int ra = wm * 128 + mi * 16 + lr;
        offA[mi] = ra * 32 + (lk ^ ((ra >> 1) & 3)) * 8;
    }
#pragma unroll
    for (int ni = 0; ni < 4; ++ni) {
        const int rb = wn * 64 + ni * 16 + lr;
        offB[ni] = rb * 32 + (lk ^ ((rb >> 1) & 3)) * 8;
    }

    auto stageA = [&](int rs, int t) {
        const int kt = t << 5;
#pragma unroll
        for (int r = 0; r < 2; ++r) {
            const int sbase = r * 512 + (w << 6);
            const int s = sbase + l;
            const int row = s >> 2;
            const int pos = s & 3;
            const int kb = pos ^ ((row >> 1) & 3);
            gld_lds16(A + (size_t)(tm + row) * lda + kt + kb * 8, &sA[rs][sbase * 8]);
        }
    };
    auto stageB = [&](int rs, int t) {
        const int kt = t << 5;
#pragma unroll
        for (int r = 0; r < 2; ++r) {
            const int sbase = r * 512 + (w << 6);
            const int s = sbase + l;
            const int row = s >> 2;
            const int pos = s & 3;
            const int kb = pos ^ ((row >> 1) & 3);
            gld_lds16(B + (size_t)(tn + row) * ldb + kt + kb * 8, &sB[rs][sbase * 8]);
        }
    };

    f32x4 acc[8][4] = {};
    f16x8 afA[4], bfA[4], afB[4], bfB[4];

    stageA(0, 0); stageB(0, 0);
    stageA(1, 1); stageB(1, 1);
    stageA(2, 2); stageB(2, 2);
    asm volatile("s_waitcnt vmcnt(8)" ::: "memory");
    __builtin_amdgcn_s_barrier();
    __builtin_amdgcn_sched_barrier(0);
#pragma unroll
    for (int i = 0; i < 4; ++i) afA[i] = *(const f16x8*)(&sA[0][0] + offA[i]);
#pragma unroll
    for (int i = 0; i < 4; ++i) bfA[i] = *(const f16x8*)(&sB[0][0] + offB[i]);

    auto tstep = [&](auto VMN, auto STG, auto LD1,
                     f16x8* af, f16x8* bf, f16x8* afn, f16x8* bfn, int t) {
        constexpr int vmn = decltype(VMN)::v;
        constexpr bool stg = decltype(STG)::v;
        constexpr bool ld1 = decltype(LD1)::v;
        const f16* sa = &sA[t & 3][0];

        __builtin_amdgcn_sched_barrier(0);
        f16x8 ag[4];
#pragma unroll
        for (int i = 0; i < 4; ++i) ag[i] = *(const f16x8*)(sa + offA[i + 4]);
        if constexpr (stg) stageA((t + 3) & 3, t + 3);
        __builtin_amdgcn_s_barrier();
        asm volatile("s_waitcnt lgkmcnt(4)" ::: "memory");
        __builtin_amdgcn_sched_barrier(0);
        __builtin_amdgcn_s_setprio(1);
#pragma unroll
        for (int mi = 0; mi < 4; ++mi)
#pragma unroll
            for (int ni = 0; ni < 4; ++ni)
                acc[mi][ni] = __builtin_amdgcn_mfma_f32_16x16x32_f16(
                    af[mi], bf[ni], acc[mi][ni], 0, 0, 0);
        __builtin_amdgcn_s_setprio(0);
        wait_vm<vmn>();
        __builtin_amdgcn_s_barrier();

        __builtin_amdgcn_sched_barrier(0);
        if constexpr (ld1) {
            const f16* na = &sA[(t + 1) & 3][0];
            const f16* nb = &sB[(t + 1) & 3][0];
#pragma unroll
            for (int i = 0; i < 4; ++i) afn[i] = *(const f16x8*)(na + offA[i]);
#pragma unroll
            for (int i = 0; i < 4; ++i) bfn[i] = *(const f16x8*)(nb + offB[i]);
        }
        if constexpr (stg) stageB((t + 3) & 3, t + 3);
        __builtin_amdgcn_s_barrier();
        if constexpr (ld1) asm volatile("s_waitcnt lgkmcnt(8)" ::: "memory");
        else               asm volatile("s_waitcnt lgkmcnt(0)" ::: "memory");
        __builtin_amdgcn_sched_barrier(0);
        __builtin_amdgcn_s_setprio(1);
#pragma unroll
        for (int mi = 0; mi < 4; ++mi)
#pragma unroll
            for (int ni = 0; ni < 4; ++ni)
                acc[mi + 4][ni] = __builtin_amdgcn_mfma_f32_16x16x32_f16(
                    ag[mi], bf[ni], acc[mi + 4][ni], 0, 0, 0);
        __builtin_amdgcn_s_setprio(0);
        __builtin_amdgcn_s_barrier();
    };

    for (int u = 0; u < NT / 2 - 2; ++u) {
        tstep(IC<6>{}, IC<true>{}, IC<true>{}, afA, bfA, afB, bfB, 2 * u);
        tstep(IC<6>{}, IC<true>{}, IC<true>{}, afB, bfB, afA, bfA, 2 * u + 1);
    }
    tstep(IC<6>{}, IC<true>{},  IC<true>{},  afA, bfA, afB, bfB, NT - 4);
    tstep(IC<4>{}, IC<false>{}, IC<true>{},  afB, bfB, afA, bfA, NT - 3);
    tstep(IC<0>{}, IC<false>{}, IC<true>{},  afA, bfA, afB, bfB, NT - 2);
    tstep(IC<0>{}, IC<false>{}, IC<false>{}, afB, bfB, afA, bfA, NT - 1);

    // ---- epilogue: E = exp(s - C) -> bf16 store + partial row sums ----
    float rs[8][4];
#pragma unroll
    for (int mi = 0; mi < 8; ++mi)
#pragma unroll
        for (int j = 0; j < 4; ++j) rs[mi][j] = 0.f;

#pragma unroll
    for (int mi = 0; mi < 8; ++mi) {
        const int r0 = tm + wm * 128 + mi * 16 + (l >> 4) * 4;
#pragma unroll
        for (int ni = 0; ni < 4; ++ni) {
            const int c0 = tn + wn * 64 + ni * 16 + lr;
#pragma unroll
            for (int j = 0; j < 4; ++j) {
                float e = __expf(acc[mi][ni][j] - SOFT_C);
                C[(size_t)(r0 + j) * ldc + c0] = f2bf(e);
                rs[mi][j] += e;
            }
        }
    }
#pragma unroll
    for (int mi = 0; mi < 8; ++mi)
#pragma unroll
        for (int j = 0; j < 4; ++j)
#pragma unroll
            for (int m = 1; m < 16; m <<= 1)
                rs[mi][j] += __shfl_xor(rs[mi][j], m, 64);

    float* lsum = (float*)&sA[0][0];   // [4 wn][256 rows]
    __syncthreads();
    if (lr == 0) {
#pragma unroll
        for (int mi = 0; mi < 8; ++mi)
#pragma unroll
            for (int j = 0; j < 4; ++j)
                lsum[wn * 256 + wm * 128 + mi * 16 + (l >> 4) * 4 + j] = rs[mi][j];
    }
    __syncthreads();
    if (tid < 256) {
        float s = (lsum[tid] + lsum[256 + tid]) + (lsum[512 + tid] + lsum[768 + tid]);
        psum[(size_t)(tn >> 8) * S_LEN + tm + tid] = s;
    }
}

// ---------------------------------------------------------------------------
// Row sums -> reciprocal
// ---------------------------------------------------------------------------
__global__ __launch_bounds__(256)
void sumrows(const float* __restrict__ ps, float* __restrict__ invR)
{
    const int r = blockIdx.x * 256 + threadIdx.x;
    float s = 0.f;
#pragma unroll
    for (int j = 0; j < 16; ++j) s += ps[(size_t)j * S_LEN + r];
    invR[r] = 1.0f / s;
}

// ---------------------------------------------------------------------------
// GEMM2: partial(bf16) = E x Vt^T (un-normalized), split-K=4, pure gld_lds
// staging (R3-proven loop), bf16 MFMA. M=4096, N=1024, Ksub=1024. 256 blocks.
// ---------------------------------------------------------------------------
__global__ __launch_bounds__(512, 2)
void gemm_bt(const unsigned short* __restrict__ A, const unsigned short* __restrict__ B,
             unsigned short* __restrict__ P)
{
    __shared__ unsigned short sA[4][256 * 32];
    __shared__ unsigned short sB[4][256 * 32];

    const int tid = threadIdx.x;
    const int w = tid >> 6;
    const int l = tid & 63;
    const int lr = l & 15;
    const int lk = l >> 4;
    const int wm = w >> 2;
    const int wn = w & 3;

    const int cpx = gridDim.x >> 3;
    const int bid = blockIdx.x;
    const int swz = (bid & 7) * cpx + (bid >> 3);
    const int split = swz & 3;
    const int tidx = swz >> 2;
    const int tm = (tidx >> 2) * 256;      // tilesN = 4
    const int tn = (tidx & 3) * 256;
    const int koff = split * 1024;
    unsigned short* Cp = P + (size_t)split * ((size_t)S_LEN * D_DIM);
    const int NT = 32;

    int offA[8], offB[4];
#pragma unroll
    for (int mi = 0; mi < 8; ++mi) {
        const int ra = wm * 128 + mi * 16 + lr;
        offA[mi] = ra * 32 + (lk ^ ((ra >> 1) & 3)) * 8;
    }
#pragma unroll
    for (int ni = 0; ni < 4; ++ni) {
        const int rb = wn * 64 + ni * 16 + lr;
        offB[ni] = rb * 32 + (lk ^ ((rb >> 1) & 3)) * 8;
    }

    auto stageA = [&](int rs, int t) {
        const int kt = koff + (t << 5);
#pragma unroll
        for (int r = 0; r < 2; ++r) {
            const int sbase = r * 512 + (w << 6);
            const int s = sbase + l;
            const int row = s >> 2;
            const int pos = s & 3;
            const int kb = pos ^ ((row >> 1) & 3);
            gld_lds16(A + (size_t)(tm + row) * S_LEN + kt + kb * 8, &sA[rs][sbase * 8]);
        }
    };
    auto stageB = [&](int rs, int t) {
        const int kt = koff + (t << 5);
#pragma unroll
        for (int r = 0; r < 2; ++r) {
            const int sbase = r * 512 + (w << 6);
            const int s = sbase + l;
            const int row = s >> 2;
            const int pos = s & 3;
            const int kb = pos ^ ((row >> 1) & 3);
            gld_lds16(B + (size_t)(tn + row) * S_LEN + kt + kb * 8, &sB[rs][sbase * 8]);
        }
    };

    f32x4 acc[8][4] = {};
    s16x8 afA[4], bfA[4], afB[4], bfB[4];

    stageA(0, 0); stageB(0, 0);
    stageA(1, 1); stageB(1, 1);
    stageA(2, 2); stageB(2, 2);
    asm volatile("s_waitcnt vmcnt(8)" ::: "memory");
    __builtin_amdgcn_s_barrier();
    __builtin_amdgcn_sched_barrier(0);
#pragma unroll
    for (int i = 0; i < 4; ++i) afA[i] = *(const s16x8*)(&sA[0][0] + offA[i]);
#pragma unroll
    for (int i = 0; i < 4; ++i) bfA[i] = *(const s16x8*)(&sB[0][0] + offB[i]);

    auto tstep = [&](auto VMN, auto STG, auto LD1,
                     s16x8* af, s16x8* bf, s16x8* afn, s16x8* bfn, int t) {
        constexpr int vmn = decltype(VMN)::v;
        constexpr bool stg = decltype(STG)::v;
        constexpr bool ld1 = decltype(LD1)::v;
        const unsigned short* sa = &sA[t & 3][0];

        __builtin_amdgcn_sched_barrier(0);
        s16x8 ag[4];
#pragma unroll
        for (int i = 0; i < 4; ++i) ag[i] = *(const s16x8*)(sa + offA[i + 4]);
        if constexpr (stg) stageA((t + 3) & 3, t + 3);
        __builtin_amdgcn_s_barrier();
        asm volatile("s_waitcnt lgkmcnt(4)" ::: "memory");
        __builtin_amdgcn_sched_barrier(0);
        __builtin_amdgcn_s_setprio(1);
#pragma unroll
        for (int mi = 0; mi < 4; ++mi)
#pragma unroll
            for (int ni = 0; ni < 4; ++ni)
                acc[mi][ni] = __builtin_amdgcn_mfma_f32_16x16x32_bf16(
                    af[mi], bf[ni], acc[mi][ni], 0, 0, 0);
        __builtin_amdgcn_s_setprio(0);
        wait_vm<vmn>();
        __builtin_amdgcn_s_barrier();

        __builtin_amdgcn_sched_barrier(0);
        if constexpr (ld1) {
            const unsigned short* na = &sA[(t + 1) & 3][0];
            const unsigned short* nb = &sB[(t + 1) & 3][0];
#pragma unroll
            for (int i = 0; i < 4; ++i) afn[i] = *(const s16x8*)(na + offA[i]);
#pragma unroll
            for (int i = 0; i < 4; ++i) bfn[i] = *(const s16x8*)(nb + offB[i]);
        }
        if constexpr (stg) stageB((t + 3) & 3, t + 3);
        __builtin_amdgcn_s_barrier();
        if constexpr (ld1) asm volatile("s_waitcnt lgkmcnt(8)" ::: "memory");
        else               asm volatile("s_waitcnt lgkmcnt(0)" ::: "memory");
        __builtin_amdgcn_sched_barrier(0);
        __builtin_amdgcn_s_setprio(1);
#pragma unroll
        for (int mi = 0; mi < 4; ++mi)
#pragma unroll
            for (int ni = 0; ni < 4; ++ni)
                acc[mi + 4][ni] = __builtin_amdgcn_mfma_f32_16x16x32_bf16(
                    ag[mi], bf[ni], acc[mi + 4][ni], 0, 0, 0);
        __builtin_amdgcn_s_setprio(0);
        __builtin_amdgcn_s_barrier();
    };

    for (int u = 0; u < NT / 2 - 2; ++u) {
        tstep(IC<6>{}, IC<true>{}, IC<true>{}, afA, bfA, afB, bfB, 2 * u);
        tstep(IC<6>{}, IC<true>{}, IC<true>{}, afB, bfB, afA, bfA, 2 * u + 1);
    }
    tstep(IC<6>{}, IC<true>{},  IC<true>{},  afA, bfA, afB, bfB, NT - 4);
    tstep(IC<4>{}, IC<false>{}, IC<true>{},  afB, bfB, afA, bfA, NT - 3);
    tstep(IC<0>{}, IC<false>{}, IC<true>{},  afA, bfA, afB, bfB, NT - 2);
    tstep(IC<0>{}, IC<false>{}, IC<false>{}, afB, bfB, afA, bfA, NT - 1);

    // epilogue: bf16 partial store
#pragma unroll
    for (int mi = 0; mi < 8; ++mi) {
        const int r0 = tm + wm * 128 + mi * 16 + (l >> 4) * 4;
#pragma unroll
        for (int ni = 0; ni < 4; ++ni) {
            const int c0 = tn + wn * 64 + ni * 16 + lr;
#pragma unroll
            for (int j = 0; j < 4; ++j)
                Cp[(size_t)(r0 + j) * D_DIM + c0] = f2bf(acc[mi][ni][j]);
        }
    }
}

// ---------------------------------------------------------------------------
// Combine 4 bf16 split-K partials, normalize by invR -> O f32
// ---------------------------------------------------------------------------
__global__ __launch_bounds__(256)
void combine4(const unsigned short* __restrict__ P, const float* __restrict__ invR,
              float* __restrict__ O)
{
    const size_t g = (size_t)blockIdx.x * 256 + threadIdx.x;  // group of 4 elems
    const size_t n = (size_t)S_LEN * D_DIM;
    const int row = (int)(g >> 8);            // 1024 cols / 4 = 256 groups/row
    const float s = invR[row];
    float4 r = {0.f, 0.f, 0.f, 0.f};
#pragma unroll
    for (int sp = 0; sp < 4; ++sp) {
        uint2 u = ((const uint2*)(P + (size_t)sp * n))[g];
        r.x += __builtin_bit_cast(float, (u.x & 0xFFFFu) << 16);
        r.y += __builtin_bit_cast(float, u.x & 0xFFFF0000u);
        r.z += __builtin_bit_cast(float, (u.y & 0xFFFFu) << 16);
        r.w += __builtin_bit_cast(float, u.y & 0xFFFF0000u);
    }
    r.x *= s; r.y *= s; r.z *= s; r.w *= s;
    ((float4*)O)[g] = r;
}

// ---------------------------------------------------------------------------
// Fallback: naive 2-pass attention
// ---------------------------------------------------------------------------
__global__ __launch_bounds__(256)
void attn_naive(const float* __restrict__ Q, const float* __restrict__ K,
                const float* __restrict__ V, float* __restrict__ O)
{
    const int r = blockIdx.x;
    const int t = threadIdx.x;
    __shared__ float red[4];
    float q[4];
#pragma unroll
    for (int i = 0; i < 4; ++i) q[i] = Q[(size_t)r * D_DIM + t + i * 256];

    float m = -1e30f;
    for (int j = 0; j < S_LEN; ++j) {
        float p = 0.f;
#pragma unroll
        for (int i = 0; i < 4; ++i) p += q[i] * K[(size_t)j * D_DIM + t + i * 256];
#pragma unroll
        for (int off = 32; off > 0; off >>= 1) p += __shfl_xor(p, off, 64);
        if ((t & 63) == 0) red[t >> 6] = p;
        __syncthreads();
        float s = (red[0] + red[1]) + (red[2] + red[3]);
        __syncthreads();
        m = fmaxf(m, s);
    }
    float acc[4] = {0.f, 0.f, 0.f, 0.f};
    float lsum = 0.f;
    for (int j = 0; j < S_LEN; ++j) {
        float p = 0.f;
#pragma unroll
        for (int i = 0; i < 4; ++i) p += q[i] * K[(size_t)j * D_DIM + t + i * 256];
#pragma unroll
        for (int off = 32; off > 0; off >>= 1) p += __shfl_xor(p, off, 64);
        if ((t & 63) == 0) red[t >> 6] = p;
        __syncthreads();
        float s = (red[0] + red[1]) + (red[2] + red[3]);
        __syncthreads();
        float e = __expf(s - m);
        lsum += e;
#pragma unroll
        for (int i = 0; i < 4; ++i) acc[i] += e * V[(size_t)j * D_DIM + t + i * 256];
    }
    const float inv = 1.f / lsum;
#pragma unroll
    for (int i = 0; i < 4; ++i) O[(size_t)r * D_DIM + t + i * 256] = acc[i] * inv;
}

// ---------------------------------------------------------------------------
extern "C" void kernel_launch(void* const* d_in, const int* in_sizes, int n_in,
                              void* d_out, int out_size, void* d_ws, size_t ws_size,
                              hipStream_t stream)
{
    const float* Q = (const float*)d_in[0];
    const float* K = (const float*)d_in[1];
    const float* V = (const float*)d_in[2];
    float* O = (float*)d_out;

    const size_t MB = 1024ull * 1024ull;
    // layout: QH 0-8, KH 8-16, VT 16-24 (bf16), E 24-56 (bf16),
    // PSUM 56-56.25, INV 56.25-56.3, P 57-89 (4 x 8MB bf16 partials)
    const size_t QH_OFF = 0;
    const size_t KH_OFF = 8 * MB;
    const size_t VT_OFF = 16 * MB;
    const size_t E_OFF  = 24 * MB;
    const size_t PS_OFF = 56 * MB;
    const size_t IV_OFF = 56 * MB + 512 * 1024;
    const size_t P_OFF  = 57 * MB;
    const size_t NEED   = 90 * MB;

    if (ws_size < NEED) {
        attn_naive<<<S_LEN, 256, 0, stream>>>(Q, K, V, O);
        return;
    }

    char* ws = (char*)d_ws;
    f16*            Qh  = (f16*)(ws + QH_OFF);
    f16*            Kh  = (f16*)(ws + KH_OFF);
    unsigned short* Vt  = (unsigned short*)(ws + VT_OFF);
    unsigned short* E   = (unsigned short*)(ws + E_OFF);
    float*          ps  = (float*)(ws + PS_OFF);
    float*          inv = (float*)(ws + IV_OFF);
    unsigned short* P   = (unsigned short*)(ws + P_OFF);

    prep<<<8192 + 4096, 256, 0, stream>>>(Q, K, V, Qh, Kh, Vt);

    // E = exp(Qh*Kh^T - C) bf16 + partial row sums
    gemm_exp<<<256, 512, 0, stream>>>(Qh, Kh, E, ps, D_DIM, D_DIM, S_LEN,
                                      D_DIM, 16);

    sumrows<<<16, 256, 0, stream>>>(ps, inv);

    // partials = E x Vt^T (un-normalized), split-K=4, bf16
    gemm_bt<<<256, 512, 0, stream>>>(E, Vt, P);

    // O = invR * sum(partials)
    combine4<<<S_LEN * D_DIM / 4 / 256, 256, 0, stream>>>(P, inv, O);
}